// Round 1
// baseline (38802.927 us; speedup 1.0000x reference)
//
#include <hip/hip_runtime.h>
#include <math.h>

// ---------------------------------------------------------------------------
// VQ-VAE forward, fp32 correctness baseline.
// Encoder: 4x [Conv2d k=4 s=2 p=1 + ReLU]
// Quantizer: argmin_c ||z - E_c||^2  (== argmin  ||E_c||^2 - 2 z.E_c), gather
// Decoder: 3x [ConvTranspose2d k=4 s=2 p=1 + ReLU] + [ConvT + tanh]
// ---------------------------------------------------------------------------

// Conv2d k=4 s=2 p=1 + ReLU. NCHW input, OIHW weights.
// One thread per output element; (n, oc) are uniform per 256-thread block
// for every layer here (OH*OW is a multiple of 256), so weight loads are
// scalar loads.
__global__ void __launch_bounds__(256) conv4s2_relu(
    const float* __restrict__ x, const float* __restrict__ w,
    const float* __restrict__ bias, float* __restrict__ y,
    int N, int Cin, int H, int W, int Cout)
{
    const int OH = H >> 1, OW = W >> 1;
    int idx = blockIdx.x * 256 + threadIdx.x;
    int total = N * Cout * OH * OW;
    if (idx >= total) return;
    int ox = idx % OW;
    int t  = idx / OW;
    int oy = t % OH; t /= OH;
    int oc = t % Cout;
    int n  = t / Cout;

    const float* xn = x + (size_t)n * Cin * H * W;
    const float* wo = w + (size_t)oc * Cin * 16;
    float acc = bias[oc];
    int iy0 = 2 * oy - 1, ix0 = 2 * ox - 1;
    for (int ic = 0; ic < Cin; ++ic) {
        const float* xc = xn + (size_t)ic * H * W;
        const float* wc = wo + ic * 16;
#pragma unroll
        for (int ky = 0; ky < 4; ++ky) {
            int iy = iy0 + ky;
            if ((unsigned)iy >= (unsigned)H) continue;
            const float* xr = xc + (size_t)iy * W;
#pragma unroll
            for (int kx = 0; kx < 4; ++kx) {
                int ix = ix0 + kx;
                if ((unsigned)ix >= (unsigned)W) continue;
                acc = fmaf(xr[ix], wc[ky * 4 + kx], acc);
            }
        }
    }
    y[idx] = fmaxf(acc, 0.0f);
}

// ConvTranspose2d k=4 s=2 p=1 (+ ReLU or tanh). Torch weight layout
// (Cin, Cout, kH, kW). out[oy] += in[iy] * w[ky] where oy = 2*iy - 1 + ky.
__global__ void __launch_bounds__(256) convt4s2_act(
    const float* __restrict__ x, const float* __restrict__ w,
    const float* __restrict__ bias, float* __restrict__ y,
    int N, int Cin, int H, int W, int Cout, int act)
{
    const int OH = H << 1, OW = W << 1;
    int idx = blockIdx.x * 256 + threadIdx.x;
    int total = N * Cout * OH * OW;
    if (idx >= total) return;
    int ox = idx % OW;
    int t  = idx / OW;
    int oy = t % OH; t /= OH;
    int co = t % Cout;
    int n  = t / Cout;

    // valid (iy,ky) / (ix,kx) taps: ky = oy + 1 - 2*iy in [0,3]
    int iys[2], kys[2], nky = 0;
    int ixs[2], kxs[2], nkx = 0;
#pragma unroll
    for (int ky = 0; ky < 4; ++ky) {
        int v = oy + 1 - ky;
        if (v & 1) continue;
        int iy = v >> 1;
        if ((unsigned)iy < (unsigned)H) { iys[nky] = iy; kys[nky] = ky; ++nky; }
    }
#pragma unroll
    for (int kx = 0; kx < 4; ++kx) {
        int v = ox + 1 - kx;
        if (v & 1) continue;
        int ix = v >> 1;
        if ((unsigned)ix < (unsigned)W) { ixs[nkx] = ix; kxs[nkx] = kx; ++nkx; }
    }

    float acc = bias[co];
    const float* xn = x + (size_t)n * Cin * H * W;
    for (int ci = 0; ci < Cin; ++ci) {
        const float* xc = xn + (size_t)ci * H * W;
        const float* wc = w + ((size_t)ci * Cout + co) * 16;
        for (int a = 0; a < nky; ++a) {
            const float* xr = xc + (size_t)iys[a] * W;
            const float* wr = wc + kys[a] * 4;
            for (int bq = 0; bq < nkx; ++bq) {
                acc = fmaf(xr[ixs[bq]], wr[kxs[bq]], acc);
            }
        }
    }
    acc = (act == 0) ? fmaxf(acc, 0.0f) : tanhf(acc);
    y[idx] = acc;
}

// ||E_c||^2 for each of the 1024 codes (dim 512).
__global__ void __launch_bounds__(256) embed_norms(
    const float* __restrict__ embed, float* __restrict__ norms)
{
    int c = blockIdx.x * 256 + threadIdx.x;  // grid = 4 blocks -> 1024 codes
    const float* e = embed + (size_t)c * 512;
    float s = 0.0f;
    for (int k = 0; k < 512; ++k) s = fmaf(e[k], e[k], s);
    norms[c] = s;
}

// One block per z-row (N*16*16 = 8192 rows). Stage z row in LDS, each thread
// scans 4 codes, then block-wide argmin (ties -> lowest index, matching
// jnp.argmin).
__global__ void __launch_bounds__(256) vq_argmin(
    const float* __restrict__ z, const float* __restrict__ embed,
    const float* __restrict__ norms, int* __restrict__ out)
{
    int row = blockIdx.x;          // n*256 + y*16 + x
    int n = row >> 8, yx = row & 255;
    __shared__ float zr[512];
    for (int c = threadIdx.x; c < 512; c += 256)
        zr[c] = z[(((size_t)n * 512 + c) << 8) + yx];
    __syncthreads();

    float best = 3.4e38f; int bi = 0;
#pragma unroll
    for (int rep = 0; rep < 4; ++rep) {
        int code = rep * 256 + threadIdx.x;
        const float* e = embed + (size_t)code * 512;
        float dot = 0.0f;
        for (int k = 0; k < 512; ++k) dot = fmaf(zr[k], e[k], dot);
        float d = norms[code] - 2.0f * dot;
        if (d < best) { best = d; bi = code; }  // strict < keeps lowest code
    }

    __shared__ float bd[256];
    __shared__ int   bix[256];
    bd[threadIdx.x] = best; bix[threadIdx.x] = bi;
    __syncthreads();
    for (int s = 128; s > 0; s >>= 1) {
        if ((int)threadIdx.x < s) {
            float od = bd[threadIdx.x + s]; int oi = bix[threadIdx.x + s];
            float md = bd[threadIdx.x];     int mi = bix[threadIdx.x];
            if (od < md || (od == md && oi < mi)) {
                bd[threadIdx.x] = od; bix[threadIdx.x] = oi;
            }
        }
        __syncthreads();
    }
    if (threadIdx.x == 0) out[row] = bix[0];
}

// zq[n][c][y][x] = embed[idx[n*256 + y*16 + x]][c]
__global__ void __launch_bounds__(256) vq_gather(
    const int* __restrict__ vidx, const float* __restrict__ embed,
    float* __restrict__ zq)
{
    int i = blockIdx.x * 256 + threadIdx.x;  // N*512*256 elements
    int yx = i & 255;
    int t  = i >> 8;
    int c  = t & 511;
    int n  = t >> 9;
    int row = (n << 8) + yx;
    zq[i] = embed[(size_t)vidx[row] * 512 + c];
}

extern "C" void kernel_launch(void* const* d_in, const int* in_sizes, int n_in,
                              void* d_out, int out_size, void* d_ws, size_t ws_size,
                              hipStream_t stream)
{
    const float* x     = (const float*)d_in[0];
    const float* ew1   = (const float*)d_in[1];
    const float* eb1   = (const float*)d_in[2];
    const float* ew2   = (const float*)d_in[3];
    const float* eb2   = (const float*)d_in[4];
    const float* ew3   = (const float*)d_in[5];
    const float* eb3   = (const float*)d_in[6];
    const float* ew4   = (const float*)d_in[7];
    const float* eb4   = (const float*)d_in[8];
    const float* dw1   = (const float*)d_in[9];
    const float* db1   = (const float*)d_in[10];
    const float* dw2   = (const float*)d_in[11];
    const float* db2   = (const float*)d_in[12];
    const float* dw3   = (const float*)d_in[13];
    const float* db3   = (const float*)d_in[14];
    const float* dw4   = (const float*)d_in[15];
    const float* db4   = (const float*)d_in[16];
    const float* embed = (const float*)d_in[17];
    float* out = (float*)d_out;

    // Ping-pong workspace: A = 33,554,432 floats (128 MiB), B = 16,777,216
    // floats (64 MiB), + idx (8192 ints) + norms (1024 floats) ~= 192 MiB.
    float* A     = (float*)d_ws;
    float* B     = A + 33554432;
    int*   vidx  = (int*)(B + 16777216);
    float* norms = (float*)(vidx + 8192);

    dim3 blk(256);
    auto g = [](int total) { return dim3((unsigned)((total + 255) / 256)); };

    // ---- encoder ----
    conv4s2_relu<<<g(32 * 64 * 128 * 128), blk, 0, stream>>>(
        x, ew1, eb1, A, 32, 3, 256, 256, 64);            // h1 -> A
    conv4s2_relu<<<g(32 * 128 * 64 * 64), blk, 0, stream>>>(
        A, ew2, eb2, B, 32, 64, 128, 128, 128);          // h2 -> B
    conv4s2_relu<<<g(32 * 256 * 32 * 32), blk, 0, stream>>>(
        B, ew3, eb3, A, 32, 128, 64, 64, 256);           // h3 -> A
    conv4s2_relu<<<g(32 * 512 * 16 * 16), blk, 0, stream>>>(
        A, ew4, eb4, B, 32, 256, 32, 32, 512);           // z  -> B

    // ---- quantizer ----
    embed_norms<<<dim3(4), blk, 0, stream>>>(embed, norms);
    vq_argmin<<<dim3(8192), blk, 0, stream>>>(B, embed, norms, vidx);
    vq_gather<<<g(32 * 512 * 16 * 16), blk, 0, stream>>>(vidx, embed, A);  // zq -> A

    // ---- decoder ----
    convt4s2_act<<<g(32 * 128 * 32 * 32), blk, 0, stream>>>(
        A, dw1, db1, B, 32, 512, 16, 16, 128, 0);        // g1 -> B
    convt4s2_act<<<g(32 * 64 * 64 * 64), blk, 0, stream>>>(
        B, dw2, db2, A, 32, 128, 32, 32, 64, 0);         // g2 -> A
    convt4s2_act<<<g(32 * 32 * 128 * 128), blk, 0, stream>>>(
        A, dw3, db3, B, 32, 64, 64, 64, 32, 0);          // g3 -> B
    convt4s2_act<<<g(32 * 3 * 256 * 256), blk, 0, stream>>>(
        B, dw4, db4, out, 32, 32, 128, 128, 3, 1);       // out (tanh)
}

// Round 2
// 9943.327 us; speedup vs baseline: 3.9024x; 3.9024x over previous
//
#include <hip/hip_runtime.h>
#include <math.h>

// ---------------------------------------------------------------------------
// VQ-VAE forward, fp32, register-tiled direct convs (4 oc x 4 ox per thread).
// ---------------------------------------------------------------------------

// Conv2d k=4 s=2 p=1 + ReLU. Each thread computes OCT oc x 4 consecutive ox.
// (n, oc0) are wave-uniform by construction -> readfirstlane makes weight
// loads scalar (constant-cache path), input loads are 10 floats per (ic,ky)
// feeding 16*OCT FMAs across 4*OCT independent accumulators.
template<int OCT>
__global__ void __launch_bounds__(256) conv4s2_relu_t(
    const float* __restrict__ x, const float* __restrict__ w,
    const float* __restrict__ bias, float* __restrict__ y,
    int N, int Cin, int H, int W, int Cout)
{
    const int OH = H >> 1, OW = W >> 1, OWq = OW >> 2;
    int id = blockIdx.x * 256 + threadIdx.x;
    int total = N * (Cout / OCT) * OH * OWq;
    if (id >= total) return;
    int ox4 = id % OWq; int t = id / OWq;
    int oy  = t % OH;   t /= OH;
    int ocg = t % (Cout / OCT);
    int n   = t / (Cout / OCT);
    // spatial threads per oc-group is a multiple of 64 for every layer here,
    // so ocg and n are wave-uniform.
    int oc0 = __builtin_amdgcn_readfirstlane(ocg * OCT);
    n       = __builtin_amdgcn_readfirstlane(n);

    int ox0 = ox4 << 2;
    int iy0 = 2 * oy - 1;
    int ix0 = 2 * ox0 - 1;               // input cols ix0 .. ix0+9

    float acc[OCT][4];
#pragma unroll
    for (int o = 0; o < OCT; ++o) {
        float b = bias[oc0 + o];
#pragma unroll
        for (int j = 0; j < 4; ++j) acc[o][j] = b;
    }

    const float* xn = x + (size_t)n * Cin * H * W;
    const bool interior = (ix0 >= 0) && (ix0 + 9 < W);

    for (int ic = 0; ic < Cin; ++ic) {
        const float* xc = xn + (size_t)ic * H * W;
        const float* wc = w + ((size_t)oc0 * Cin + ic) * 16;
#pragma unroll
        for (int ky = 0; ky < 4; ++ky) {
            int iy = iy0 + ky;
            if ((unsigned)iy >= (unsigned)H) continue;
            const float* xr = xc + (size_t)iy * W;
            float xv[10];
            if (interior) {
#pragma unroll
                for (int j = 0; j < 10; ++j) xv[j] = xr[ix0 + j];
            } else {
#pragma unroll
                for (int j = 0; j < 10; ++j) {
                    int ix = ix0 + j;
                    xv[j] = ((unsigned)ix < (unsigned)W) ? xr[ix] : 0.0f;
                }
            }
#pragma unroll
            for (int o = 0; o < OCT; ++o) {
                const float* wr = wc + (size_t)o * Cin * 16 + ky * 4;
                float w0 = wr[0], w1 = wr[1], w2 = wr[2], w3 = wr[3];
#pragma unroll
                for (int j = 0; j < 4; ++j) {
                    acc[o][j] = fmaf(xv[2 * j],     w0, acc[o][j]);
                    acc[o][j] = fmaf(xv[2 * j + 1], w1, acc[o][j]);
                    acc[o][j] = fmaf(xv[2 * j + 2], w2, acc[o][j]);
                    acc[o][j] = fmaf(xv[2 * j + 3], w3, acc[o][j]);
                }
            }
        }
    }
#pragma unroll
    for (int o = 0; o < OCT; ++o) {
        float* yr = y + (((size_t)n * Cout + oc0 + o) * OH + oy) * OW + ox0;
#pragma unroll
        for (int j = 0; j < 4; ++j) yr[j] = fmaxf(acc[o][j], 0.0f);
    }
}

// ConvTranspose2d k=4 s=2 p=1 (+ ReLU / tanh). Torch weights (Cin,Cout,4,4).
// Thread tile: COT co x 4 consecutive ox (fixed oy). For the 4 ox the needed
// input cols are xv[0..3] = x[t0-1 .. t0+2], t0 = ox0/2.
template<int COT>
__global__ void __launch_bounds__(256) convt4s2_t(
    const float* __restrict__ x, const float* __restrict__ w,
    const float* __restrict__ bias, float* __restrict__ y,
    int N, int Cin, int H, int W, int Cout, int act)
{
    const int OH = H << 1, OW = W << 1, OWq = OW >> 2;
    int id = blockIdx.x * 256 + threadIdx.x;
    int total = N * (Cout / COT) * OH * OWq;
    if (id >= total) return;
    int ox4 = id % OWq; int t = id / OWq;
    int oy  = t % OH;   t /= OH;
    int cog = t % (Cout / COT);
    int n   = t / (Cout / COT);
    int co0 = __builtin_amdgcn_readfirstlane(cog * COT);
    n       = __builtin_amdgcn_readfirstlane(n);

    int ox0 = ox4 << 2;
    int t0  = ox4 << 1;                  // ox0 / 2

    // valid (iy, ky) taps for this oy (1 or 2 of them)
    int iys[2], kys[2], nky = 0;
#pragma unroll
    for (int ky = 0; ky < 4; ++ky) {
        int v = oy + 1 - ky;
        if (v & 1) continue;
        int iy = v >> 1;
        if ((unsigned)iy < (unsigned)H) { iys[nky] = iy; kys[nky] = ky; ++nky; }
    }

    float acc[COT][4];
#pragma unroll
    for (int o = 0; o < COT; ++o) {
        float b = bias[co0 + o];
#pragma unroll
        for (int j = 0; j < 4; ++j) acc[o][j] = b;
    }

    const float* xn = x + (size_t)n * Cin * H * W;
    const bool interior = (t0 - 1 >= 0) && (t0 + 2 < W);

    for (int ci = 0; ci < Cin; ++ci) {
        const float* xc = xn + (size_t)ci * H * W;
        const float* wci = w + ((size_t)ci * Cout + co0) * 16;
        for (int a = 0; a < nky; ++a) {
            const float* xr = xc + (size_t)iys[a] * W;
            float xv[4];
            if (interior) {
#pragma unroll
                for (int j = 0; j < 4; ++j) xv[j] = xr[t0 - 1 + j];
            } else {
#pragma unroll
                for (int j = 0; j < 4; ++j) {
                    int ix = t0 - 1 + j;
                    xv[j] = ((unsigned)ix < (unsigned)W) ? xr[ix] : 0.0f;
                }
            }
            int kb = kys[a] * 4;
#pragma unroll
            for (int o = 0; o < COT; ++o) {
                const float* wr = wci + (size_t)o * 16 + kb;
                float w0 = wr[0], w1 = wr[1], w2 = wr[2], w3 = wr[3];
                // ox0:   kx=1 -> xv[1], kx=3 -> xv[0]
                acc[o][0] = fmaf(xv[1], w1, acc[o][0]);
                acc[o][0] = fmaf(xv[0], w3, acc[o][0]);
                // ox0+1: kx=0 -> xv[2], kx=2 -> xv[1]
                acc[o][1] = fmaf(xv[2], w0, acc[o][1]);
                acc[o][1] = fmaf(xv[1], w2, acc[o][1]);
                // ox0+2: kx=1 -> xv[2], kx=3 -> xv[1]
                acc[o][2] = fmaf(xv[2], w1, acc[o][2]);
                acc[o][2] = fmaf(xv[1], w3, acc[o][2]);
                // ox0+3: kx=0 -> xv[3], kx=2 -> xv[2]
                acc[o][3] = fmaf(xv[3], w0, acc[o][3]);
                acc[o][3] = fmaf(xv[2], w2, acc[o][3]);
            }
        }
    }
#pragma unroll
    for (int o = 0; o < COT; ++o) {
        float* yr = y + (((size_t)n * Cout + co0 + o) * OH + oy) * OW + ox0;
#pragma unroll
        for (int j = 0; j < 4; ++j) {
            float v = acc[o][j];
            yr[j] = (act == 0) ? fmaxf(v, 0.0f) : tanhf(v);
        }
    }
}

// ||E_c||^2 for each of the 1024 codes (dim 512).
__global__ void __launch_bounds__(256) embed_norms(
    const float* __restrict__ embed, float* __restrict__ norms)
{
    int c = blockIdx.x * 256 + threadIdx.x;
    const float* e = embed + (size_t)c * 512;
    float s = 0.0f;
    for (int k = 0; k < 512; ++k) s = fmaf(e[k], e[k], s);
    norms[c] = s;
}

// One block per z-row. argmin_c ||E_c||^2 - 2 z.E_c (ties -> lowest index).
__global__ void __launch_bounds__(256) vq_argmin(
    const float* __restrict__ z, const float* __restrict__ embed,
    const float* __restrict__ norms, int* __restrict__ out)
{
    int row = blockIdx.x;          // n*256 + y*16 + x
    int n = row >> 8, yx = row & 255;
    __shared__ float zr[512];
    for (int c = threadIdx.x; c < 512; c += 256)
        zr[c] = z[(((size_t)n * 512 + c) << 8) + yx];
    __syncthreads();

    float best = 3.4e38f; int bi = 0;
#pragma unroll
    for (int rep = 0; rep < 4; ++rep) {
        int code = rep * 256 + threadIdx.x;
        const float* e = embed + (size_t)code * 512;
        float dot = 0.0f;
        for (int k = 0; k < 512; ++k) dot = fmaf(zr[k], e[k], dot);
        float d = norms[code] - 2.0f * dot;
        if (d < best) { best = d; bi = code; }
    }

    __shared__ float bd[256];
    __shared__ int   bix[256];
    bd[threadIdx.x] = best; bix[threadIdx.x] = bi;
    __syncthreads();
    for (int s = 128; s > 0; s >>= 1) {
        if ((int)threadIdx.x < s) {
            float od = bd[threadIdx.x + s]; int oi = bix[threadIdx.x + s];
            float md = bd[threadIdx.x];     int mi = bix[threadIdx.x];
            if (od < md || (od == md && oi < mi)) {
                bd[threadIdx.x] = od; bix[threadIdx.x] = oi;
            }
        }
        __syncthreads();
    }
    if (threadIdx.x == 0) out[row] = bix[0];
}

// zq[n][c][y][x] = embed[idx[n*256 + y*16 + x]][c]
__global__ void __launch_bounds__(256) vq_gather(
    const int* __restrict__ vidx, const float* __restrict__ embed,
    float* __restrict__ zq)
{
    int i = blockIdx.x * 256 + threadIdx.x;
    int yx = i & 255;
    int t  = i >> 8;
    int c  = t & 511;
    int n  = t >> 9;
    int row = (n << 8) + yx;
    zq[i] = embed[(size_t)vidx[row] * 512 + c];
}

extern "C" void kernel_launch(void* const* d_in, const int* in_sizes, int n_in,
                              void* d_out, int out_size, void* d_ws, size_t ws_size,
                              hipStream_t stream)
{
    const float* x     = (const float*)d_in[0];
    const float* ew1   = (const float*)d_in[1];
    const float* eb1   = (const float*)d_in[2];
    const float* ew2   = (const float*)d_in[3];
    const float* eb2   = (const float*)d_in[4];
    const float* ew3   = (const float*)d_in[5];
    const float* eb3   = (const float*)d_in[6];
    const float* ew4   = (const float*)d_in[7];
    const float* eb4   = (const float*)d_in[8];
    const float* dw1   = (const float*)d_in[9];
    const float* db1   = (const float*)d_in[10];
    const float* dw2   = (const float*)d_in[11];
    const float* db2   = (const float*)d_in[12];
    const float* dw3   = (const float*)d_in[13];
    const float* db3   = (const float*)d_in[14];
    const float* dw4   = (const float*)d_in[15];
    const float* db4   = (const float*)d_in[16];
    const float* embed = (const float*)d_in[17];
    float* out = (float*)d_out;

    float* A     = (float*)d_ws;                 // 128 MiB
    float* B     = A + 33554432;                 // 64 MiB
    int*   vidx  = (int*)(B + 16777216);
    float* norms = (float*)(vidx + 8192);

    dim3 blk(256);
    auto g = [](int total_threads) {
        return dim3((unsigned)((total_threads + 255) / 256));
    };

    // ---- encoder ----  (thread tiles: 4 oc x 4 ox)
    conv4s2_relu_t<4><<<g(32 * (64 / 4) * 128 * (128 / 4)), blk, 0, stream>>>(
        x, ew1, eb1, A, 32, 3, 256, 256, 64);           // h1 -> A
    conv4s2_relu_t<4><<<g(32 * (128 / 4) * 64 * (64 / 4)), blk, 0, stream>>>(
        A, ew2, eb2, B, 32, 64, 128, 128, 128);         // h2 -> B
    conv4s2_relu_t<4><<<g(32 * (256 / 4) * 32 * (32 / 4)), blk, 0, stream>>>(
        B, ew3, eb3, A, 32, 128, 64, 64, 256);          // h3 -> A
    conv4s2_relu_t<4><<<g(32 * (512 / 4) * 16 * (16 / 4)), blk, 0, stream>>>(
        A, ew4, eb4, B, 32, 256, 32, 32, 512);          // z  -> B

    // ---- quantizer ----
    embed_norms<<<dim3(4), blk, 0, stream>>>(embed, norms);
    vq_argmin<<<dim3(8192), blk, 0, stream>>>(B, embed, norms, vidx);
    vq_gather<<<g(32 * 512 * 256), blk, 0, stream>>>(vidx, embed, A);  // zq -> A

    // ---- decoder ----  (thread tiles: 4 co x 4 ox; final layer 3 co x 4 ox)
    convt4s2_t<4><<<g(32 * (128 / 4) * 32 * (32 / 4)), blk, 0, stream>>>(
        A, dw1, db1, B, 32, 512, 16, 16, 128, 0);       // g1 -> B
    convt4s2_t<4><<<g(32 * (64 / 4) * 64 * (64 / 4)), blk, 0, stream>>>(
        B, dw2, db2, A, 32, 128, 32, 32, 64, 0);        // g2 -> A
    convt4s2_t<4><<<g(32 * (32 / 4) * 128 * (128 / 4)), blk, 0, stream>>>(
        A, dw3, db3, B, 32, 64, 64, 64, 32, 0);         // g3 -> B
    convt4s2_t<3><<<g(32 * (3 / 3) * 256 * (256 / 4)), blk, 0, stream>>>(
        B, dw4, db4, out, 32, 32, 128, 128, 3, 1);      // out (tanh)
}

// Round 3
// 8687.186 us; speedup vs baseline: 4.4667x; 1.1446x over previous
//
#include <hip/hip_runtime.h>
#include <math.h>

// ---------------------------------------------------------------------------
// VQ-VAE forward, fp32. Round 3: compile-time dims, branchless interior /
// masked border paths, 8-row LDS-tiled VQ argmin.
// ---------------------------------------------------------------------------

// ---- Conv2d k=4 s=2 p=1 + ReLU core (INT = interior, no bounds logic) ----
template<int Cin, int H, int W, int OCT, int UNR, bool INT>
__device__ __forceinline__ void conv_core(
    const float* __restrict__ xn, const float* __restrict__ wbase,
    int iy0, int ix0, float (&acc)[OCT][4])
{
#pragma unroll UNR
    for (int ic = 0; ic < Cin; ++ic) {
        const float* xc = xn + (size_t)ic * (H * W);
        float xv[4][10];
#pragma unroll
        for (int ky = 0; ky < 4; ++ky) {
            int iy = iy0 + ky;
            if (INT) {
                const float* xr = xc + (size_t)iy * W;
#pragma unroll
                for (int j = 0; j < 10; ++j) xv[ky][j] = xr[ix0 + j];
            } else {
                bool rv = ((unsigned)iy < (unsigned)H);
                const float* xr = xc + (size_t)(rv ? iy : 0) * W;
#pragma unroll
                for (int j = 0; j < 10; ++j) {
                    int ix = ix0 + j;
                    bool cv = rv && ((unsigned)ix < (unsigned)W);
                    int ixc = cv ? ix : 0;               // clamped, in-bounds
                    xv[ky][j] = cv ? xr[ixc] : 0.0f;
                }
            }
        }
#pragma unroll
        for (int o = 0; o < OCT; ++o) {
            const float* wr = wbase + (size_t)o * (Cin * 16) + ic * 16;
#pragma unroll
            for (int ky = 0; ky < 4; ++ky) {
                float w0 = wr[ky * 4 + 0], w1 = wr[ky * 4 + 1];
                float w2 = wr[ky * 4 + 2], w3 = wr[ky * 4 + 3];
#pragma unroll
                for (int j = 0; j < 4; ++j) {
                    acc[o][j] = fmaf(xv[ky][2 * j],     w0, acc[o][j]);
                    acc[o][j] = fmaf(xv[ky][2 * j + 1], w1, acc[o][j]);
                    acc[o][j] = fmaf(xv[ky][2 * j + 2], w2, acc[o][j]);
                    acc[o][j] = fmaf(xv[ky][2 * j + 3], w3, acc[o][j]);
                }
            }
        }
    }
}

template<int Cin, int H, int W, int Cout, int OCT, int UNR>
__global__ void __launch_bounds__(256) conv4s2_k(
    const float* __restrict__ x, const float* __restrict__ w,
    const float* __restrict__ bias, float* __restrict__ y)
{
    constexpr int OH = H / 2, OW = W / 2, OWq = OW / 4;
    int id = blockIdx.x * 256 + threadIdx.x;     // grid sized exactly
    int ox4 = id % OWq; int t = id / OWq;
    int oy  = t % OH;   t /= OH;
    int ocg = t % (Cout / OCT);
    int n   = t / (Cout / OCT);
    int oc0 = __builtin_amdgcn_readfirstlane(ocg * OCT);
    n       = __builtin_amdgcn_readfirstlane(n);

    float acc[OCT][4];
#pragma unroll
    for (int o = 0; o < OCT; ++o) {
        float b = bias[oc0 + o];
#pragma unroll
        for (int j = 0; j < 4; ++j) acc[o][j] = b;
    }

    const float* xn    = x + (size_t)n * Cin * H * W;
    const float* wbase = w + (size_t)oc0 * Cin * 16;
    int iy0 = 2 * oy - 1;
    int ix0 = 8 * ox4 - 1;

    bool interior = (oy >= 1) && (oy <= OH - 2) && (ox4 >= 1) && (ox4 <= OWq - 2);
    if (interior) conv_core<Cin, H, W, OCT, UNR, true >(xn, wbase, iy0, ix0, acc);
    else          conv_core<Cin, H, W, OCT, UNR, false>(xn, wbase, iy0, ix0, acc);

    int ox0 = ox4 * 4;
#pragma unroll
    for (int o = 0; o < OCT; ++o) {
        float* yr = y + (((size_t)n * Cout + oc0 + o) * OH + oy) * OW + ox0;
#pragma unroll
        for (int j = 0; j < 4; ++j) yr[j] = fmaxf(acc[o][j], 0.0f);
    }
}

// ---- ConvTranspose2d k=4 s=2 p=1 (+ReLU / tanh), branchless 2-tap form ----
// Torch weights (Cin, Cout, 4, 4). For output row oy: ky taps {p, p+2},
// p = (oy+1)&1, rows iyA=(oy+1-p)/2 and iyB=iyA-1 (masked if OOB).
template<int Cin, int H, int W, int Cout, int COT, int ACT, int UNR>
__global__ void __launch_bounds__(256) convt4s2_k(
    const float* __restrict__ x, const float* __restrict__ w,
    const float* __restrict__ bias, float* __restrict__ y)
{
    constexpr int OH = 2 * H, OW = 2 * W, OWq = OW / 4;
    int id = blockIdx.x * 256 + threadIdx.x;
    int ox4 = id % OWq; int t = id / OWq;
    int oy  = t % OH;   t /= OH;
    int cog = t % (Cout / COT);
    int n   = t / (Cout / COT);
    int co0 = __builtin_amdgcn_readfirstlane(cog * COT);
    n       = __builtin_amdgcn_readfirstlane(n);

    int p   = (oy + 1) & 1;
    int iyA = (oy + 1 - p) >> 1;           // tap ky = p
    int iyB = iyA - 1;                     // tap ky = p + 2
    bool vA = (iyA < H);
    bool vB = (iyB >= 0);
    int iyAc = vA ? iyA : 0, iyBc = vB ? iyB : 0;

    int t0 = 2 * ox4 * 2;                  // = ox0/2 with ox0 = 4*ox4
    t0 = 2 * ox4;                          // (ox0 = 4*ox4 -> t0 = 2*ox4)
    bool c0 = (t0 - 1 >= 0);
    bool c3 = (t0 + 2 <= W - 1);
    int j0 = c0 ? t0 - 1 : 0;
    int j3 = c3 ? t0 + 2 : 0;

    float acc[COT][4];
#pragma unroll
    for (int o = 0; o < COT; ++o) {
        float b = bias[co0 + o];
#pragma unroll
        for (int j = 0; j < 4; ++j) acc[o][j] = b;
    }

    const float* xn = x + (size_t)n * Cin * H * W;

#pragma unroll UNR
    for (int ci = 0; ci < Cin; ++ci) {
        const float* xc  = xn + (size_t)ci * (H * W);
        const float* xrA = xc + (size_t)iyAc * W;
        const float* xrB = xc + (size_t)iyBc * W;
        float a0 = (vA && c0) ? xrA[j0]     : 0.0f;
        float a1 =  vA        ? xrA[t0]     : 0.0f;
        float a2 =  vA        ? xrA[t0 + 1] : 0.0f;
        float a3 = (vA && c3) ? xrA[j3]     : 0.0f;
        float b0 = (vB && c0) ? xrB[j0]     : 0.0f;
        float b1 =  vB        ? xrB[t0]     : 0.0f;
        float b2 =  vB        ? xrB[t0 + 1] : 0.0f;
        float b3 = (vB && c3) ? xrB[j3]     : 0.0f;

        const float* wci = w + ((size_t)ci * Cout + co0) * 16;
#pragma unroll
        for (int o = 0; o < COT; ++o) {
            const float* wr = wci + (size_t)o * 16;
            float wA0 = wr[p * 4 + 0], wA1 = wr[p * 4 + 1];
            float wA2 = wr[p * 4 + 2], wA3 = wr[p * 4 + 3];
            float wB0 = wr[(p + 2) * 4 + 0], wB1 = wr[(p + 2) * 4 + 1];
            float wB2 = wr[(p + 2) * 4 + 2], wB3 = wr[(p + 2) * 4 + 3];
            acc[o][0] = fmaf(a1, wA1, acc[o][0]); acc[o][0] = fmaf(a0, wA3, acc[o][0]);
            acc[o][0] = fmaf(b1, wB1, acc[o][0]); acc[o][0] = fmaf(b0, wB3, acc[o][0]);
            acc[o][1] = fmaf(a2, wA0, acc[o][1]); acc[o][1] = fmaf(a1, wA2, acc[o][1]);
            acc[o][1] = fmaf(b2, wB0, acc[o][1]); acc[o][1] = fmaf(b1, wB2, acc[o][1]);
            acc[o][2] = fmaf(a2, wA1, acc[o][2]); acc[o][2] = fmaf(a1, wA3, acc[o][2]);
            acc[o][2] = fmaf(b2, wB1, acc[o][2]); acc[o][2] = fmaf(b1, wB3, acc[o][2]);
            acc[o][3] = fmaf(a3, wA0, acc[o][3]); acc[o][3] = fmaf(a2, wA2, acc[o][3]);
            acc[o][3] = fmaf(b3, wB0, acc[o][3]); acc[o][3] = fmaf(b2, wB2, acc[o][3]);
        }
    }

    int ox0 = ox4 * 4;
#pragma unroll
    for (int o = 0; o < COT; ++o) {
        float* yr = y + (((size_t)n * Cout + co0 + o) * OH + oy) * OW + ox0;
#pragma unroll
        for (int j = 0; j < 4; ++j) {
            float v = acc[o][j];
            yr[j] = (ACT == 0) ? fmaxf(v, 0.0f) : tanhf(v);
        }
    }
}

// ---- ||E_c||^2 ----
__global__ void __launch_bounds__(256) embed_norms(
    const float* __restrict__ embed, float* __restrict__ norms)
{
    int c = blockIdx.x * 256 + threadIdx.x;
    const float* e = embed + (size_t)c * 512;
    float s = 0.0f;
    for (int k = 0; k < 512; ++k) s = fmaf(e[k], e[k], s);
    norms[c] = s;
}

// ---- VQ argmin, 8 rows per block (amortize embed reads 8x) ----
__global__ void __launch_bounds__(256) vq_argmin8(
    const float* __restrict__ z, const float* __restrict__ embed,
    const float* __restrict__ norms, int* __restrict__ out)
{
    int row0 = blockIdx.x * 8;             // row = n*256 + yx; 32 blocks per n
    int n    = row0 >> 8;
    int yx0  = row0 & 255;

    __shared__ float zr[8 * 512];          // zr[r*512 + c]
    const float* zn = z + ((size_t)n * 512) * 256;
    for (int i = threadIdx.x; i < 8 * 512; i += 256) {
        int r = i >> 9, c = i & 511;
        zr[i] = zn[((size_t)c << 8) + yx0 + r];
    }
    __syncthreads();

    float best[8]; int bi[8];
#pragma unroll
    for (int r = 0; r < 8; ++r) { best[r] = 3.4e38f; bi[r] = 0; }

#pragma unroll
    for (int rep = 0; rep < 4; ++rep) {
        int code = rep * 256 + threadIdx.x;
        const float4* e4 = (const float4*)(embed + (size_t)code * 512);
        float dot[8];
#pragma unroll
        for (int r = 0; r < 8; ++r) dot[r] = 0.0f;
        for (int k4 = 0; k4 < 128; ++k4) {
            float4 e = e4[k4];
#pragma unroll
            for (int r = 0; r < 8; ++r) {
                const float4 zz = *(const float4*)&zr[r * 512 + k4 * 4];
                dot[r] = fmaf(e.x, zz.x, dot[r]);
                dot[r] = fmaf(e.y, zz.y, dot[r]);
                dot[r] = fmaf(e.z, zz.z, dot[r]);
                dot[r] = fmaf(e.w, zz.w, dot[r]);
            }
        }
        float nb = norms[code];
#pragma unroll
        for (int r = 0; r < 8; ++r) {
            float d = nb - 2.0f * dot[r];
            if (d < best[r]) { best[r] = d; bi[r] = code; }  // ascending codes
        }
    }

    __shared__ float rbd[8 * 256];
    __shared__ int   rbi[8 * 256];
#pragma unroll
    for (int r = 0; r < 8; ++r) {
        rbd[r * 256 + threadIdx.x] = best[r];
        rbi[r * 256 + threadIdx.x] = bi[r];
    }
    __syncthreads();
    for (int s = 128; s > 0; s >>= 1) {
        if ((int)threadIdx.x < s) {
#pragma unroll
            for (int r = 0; r < 8; ++r) {
                int i0 = r * 256 + threadIdx.x;
                float od = rbd[i0 + s]; int oi = rbi[i0 + s];
                float md = rbd[i0];     int mi = rbi[i0];
                if (od < md || (od == md && oi < mi)) { rbd[i0] = od; rbi[i0] = oi; }
            }
        }
        __syncthreads();
    }
    if (threadIdx.x < 8) out[row0 + threadIdx.x] = rbi[threadIdx.x * 256];
}

// ---- gather: zq[n][c][y][x] = embed[idx[row]][c] ----
__global__ void __launch_bounds__(256) vq_gather(
    const int* __restrict__ vidx, const float* __restrict__ embed,
    float* __restrict__ zq)
{
    int i = blockIdx.x * 256 + threadIdx.x;
    int yx = i & 255;
    int t  = i >> 8;
    int c  = t & 511;
    int n  = t >> 9;
    int row = (n << 8) + yx;
    zq[i] = embed[(size_t)vidx[row] * 512 + c];
}

extern "C" void kernel_launch(void* const* d_in, const int* in_sizes, int n_in,
                              void* d_out, int out_size, void* d_ws, size_t ws_size,
                              hipStream_t stream)
{
    (void)in_sizes; (void)n_in; (void)out_size; (void)ws_size;
    const float* x     = (const float*)d_in[0];
    const float* ew1   = (const float*)d_in[1];
    const float* eb1   = (const float*)d_in[2];
    const float* ew2   = (const float*)d_in[3];
    const float* eb2   = (const float*)d_in[4];
    const float* ew3   = (const float*)d_in[5];
    const float* eb3   = (const float*)d_in[6];
    const float* ew4   = (const float*)d_in[7];
    const float* eb4   = (const float*)d_in[8];
    const float* dw1   = (const float*)d_in[9];
    const float* db1   = (const float*)d_in[10];
    const float* dw2   = (const float*)d_in[11];
    const float* db2   = (const float*)d_in[12];
    const float* dw3   = (const float*)d_in[13];
    const float* db3   = (const float*)d_in[14];
    const float* dw4   = (const float*)d_in[15];
    const float* db4   = (const float*)d_in[16];
    const float* embed = (const float*)d_in[17];
    float* out = (float*)d_out;

    float* A     = (float*)d_ws;                 // 128 MiB  (proven layout)
    float* B     = A + 33554432;                 // 64 MiB
    int*   vidx  = (int*)(B + 16777216);
    float* norms = (float*)(vidx + 8192);

    dim3 blk(256);

    // ---- encoder ----
    conv4s2_k<3, 256, 256, 64, 4, 3><<<dim3(8192), blk, 0, stream>>>(
        x, ew1, eb1, A);                          // h1 -> A
    conv4s2_k<64, 128, 128, 128, 8, 2><<<dim3(2048), blk, 0, stream>>>(
        A, ew2, eb2, B);                          // h2 -> B
    conv4s2_k<128, 64, 64, 256, 4, 2><<<dim3(2048), blk, 0, stream>>>(
        B, ew3, eb3, A);                          // h3 -> A
    conv4s2_k<256, 32, 32, 512, 4, 2><<<dim3(1024), blk, 0, stream>>>(
        A, ew4, eb4, B);                          // z  -> B

    // ---- quantizer ----
    embed_norms<<<dim3(4), blk, 0, stream>>>(embed, norms);
    vq_argmin8<<<dim3(1024), blk, 0, stream>>>(B, embed, norms, vidx);
    vq_gather<<<dim3(16384), blk, 0, stream>>>(vidx, embed, A);   // zq -> A

    // ---- decoder ----
    convt4s2_k<512, 16, 16, 128, 4, 0, 4><<<dim3(1024), blk, 0, stream>>>(
        A, dw1, db1, B);                          // g1 -> B
    convt4s2_k<128, 32, 32, 64, 4, 0, 4><<<dim3(2048), blk, 0, stream>>>(
        B, dw2, db2, A);                          // g2 -> A
    convt4s2_k<64, 64, 64, 32, 4, 0, 2><<<dim3(4096), blk, 0, stream>>>(
        A, dw3, db3, B);                          // g3 -> B
    convt4s2_k<32, 128, 128, 3, 3, 1, 2><<<dim3(2048), blk, 0, stream>>>(
        B, dw4, db4, out);                        // out (tanh)
}

// Round 4
// 3699.413 us; speedup vs baseline: 10.4889x; 2.3483x over previous
//
#include <hip/hip_runtime.h>
#include <math.h>

// ---------------------------------------------------------------------------
// VQ-VAE forward, fp32. Round 4: LDS-staged conv/convT with register-prefetch
// double buffering. conv1/g4 keep the direct kernels; VQ unchanged.
// ---------------------------------------------------------------------------

// ======================= LDS-staged Conv2d k=4 s=2 p=1 + ReLU ==============
// Block: 256 threads, output tile 16x16 spatial x 32 oc.
// Thread: 2 oy x 4 ox x 4 oc = 32 accumulators.
// LDS: xs[4][34][36] input chunk (halo'd, col-shifted +1, stride 36 for b128
//      alignment), ws[4][16][36] weights [icc][ky*4+kx][oc_local].
template<int Cin, int H, int W, int Cout>
__global__ void __launch_bounds__(256) conv4s2_lds(
    const float* __restrict__ x, const float* __restrict__ w,
    const float* __restrict__ bias, float* __restrict__ y)
{
    constexpr int OH = H / 2, OW = W / 2;
    constexpr int SPX = OW / 16, SPT = (OH / 16) * SPX;
    constexpr int NC = Cin / 4;                 // chunks of 4 input channels
    constexpr int XEL = 4 * 34 * 36;            // LDS input floats (incl pad)
    constexpr int XIT = (XEL + 255) / 256;      // 20
    constexpr int WEL = 4 * 16 * 32;            // weight elements per chunk
    constexpr int WIT = WEL / 256;              // 8

    __shared__ float xs[4][34][36];
    __shared__ float ws[4][16][36];

    int bid = blockIdx.x;
    int st  = bid % SPT; int t = bid / SPT;
    int ocg = t % (Cout / 32);
    int n   = t / (Cout / 32);
    int oyb = (st / SPX) * 16, oxb = (st % SPX) * 16;
    int oc0 = ocg * 32;

    int tid = threadIdx.x;
    int tx = tid & 3, ty = (tid >> 2) & 7, tc = tid >> 5;

    float acc[2][4][4];                          // [r][o][j]
#pragma unroll
    for (int o = 0; o < 4; ++o) {
        float b = bias[oc0 + 4 * tc + o];
#pragma unroll
        for (int r = 0; r < 2; ++r)
#pragma unroll
            for (int j = 0; j < 4; ++j) acc[r][o][j] = b;
    }

    const float* xn = x + (size_t)n * Cin * H * W;
    float pfx[XIT];
    float pfw[WIT];

    // ---- chunk loader (global -> regs). Index math is chunk-invariant
    // except the +c0 channel offset; compiler hoists the div/mod chains. ----
    auto load_chunk = [&](int c0) {
#pragma unroll
        for (int k = 0; k < XIT; ++k) {
            int i = tid + 256 * k;
            float v = 0.0f;
            if (i < XEL) {
                int lc  = i % 36;
                int r2  = i / 36;
                int lr  = r2 % 34;
                int icc = r2 / 34;
                int gr = 2 * oyb - 1 + lr;
                int gc = 2 * oxb - 1 + lc;
                if ((unsigned)gr < (unsigned)H && (unsigned)gc < (unsigned)W)
                    v = xn[((size_t)(c0 + icc) * H + gr) * W + gc];
            }
            pfx[k] = v;
        }
#pragma unroll
        for (int k = 0; k < WIT; ++k) {
            int i = tid + 256 * k;
            int kk  = i & 15;
            int icc = (i >> 4) & 3;
            int ocl = i >> 6;
            pfw[k] = w[((size_t)(oc0 + ocl) * Cin + c0 + icc) * 16 + kk];
        }
    };
    auto store_chunk = [&]() {
#pragma unroll
        for (int k = 0; k < XIT; ++k) {
            int i = tid + 256 * k;
            if (i < XEL) ((float*)xs)[i] = pfx[k];
        }
#pragma unroll
        for (int k = 0; k < WIT; ++k) {
            int i = tid + 256 * k;
            int kk  = i & 15;
            int icc = (i >> 4) & 3;
            int ocl = i >> 6;
            ws[icc][kk][ocl] = pfw[k];
        }
    };

    load_chunk(0);
#pragma unroll 1
    for (int c = 0; c < NC; ++c) {
        __syncthreads();
        store_chunk();
        __syncthreads();
        if (c + 1 < NC) load_chunk((c + 1) * 4);

#pragma unroll 1
        for (int icc = 0; icc < 4; ++icc) {
#pragma unroll
            for (int ky = 0; ky < 4; ++ky) {
                float4 wv[4];
#pragma unroll
                for (int kx = 0; kx < 4; ++kx)
                    wv[kx] = *(const float4*)&ws[icc][ky * 4 + kx][4 * tc];
#pragma unroll
                for (int r = 0; r < 2; ++r) {
                    const float* row = &xs[icc][4 * ty + 2 * r + ky][8 * tx];
                    float4 a  = *(const float4*)row;
                    float4 b  = *(const float4*)(row + 4);
                    float2 cc = *(const float2*)(row + 8);
                    float xv[10] = {a.x, a.y, a.z, a.w,
                                    b.x, b.y, b.z, b.w, cc.x, cc.y};
#pragma unroll
                    for (int j = 0; j < 4; ++j)
#pragma unroll
                        for (int kx = 0; kx < 4; ++kx) {
                            float xval = xv[2 * j + kx];
                            acc[r][0][j] = fmaf(xval, wv[kx].x, acc[r][0][j]);
                            acc[r][1][j] = fmaf(xval, wv[kx].y, acc[r][1][j]);
                            acc[r][2][j] = fmaf(xval, wv[kx].z, acc[r][2][j]);
                            acc[r][3][j] = fmaf(xval, wv[kx].w, acc[r][3][j]);
                        }
                }
            }
        }
    }

#pragma unroll
    for (int r = 0; r < 2; ++r) {
        int oy = oyb + 2 * ty + r;
#pragma unroll
        for (int o = 0; o < 4; ++o) {
            float* yr = y + (((size_t)n * Cout + oc0 + 4 * tc + o) * OH + oy) * OW
                          + oxb + 4 * tx;
            float4 v;
            v.x = fmaxf(acc[r][o][0], 0.0f);
            v.y = fmaxf(acc[r][o][1], 0.0f);
            v.z = fmaxf(acc[r][o][2], 0.0f);
            v.w = fmaxf(acc[r][o][3], 0.0f);
            *(float4*)yr = v;
        }
    }
}

// =============== LDS-staged ConvTranspose2d k=4 s=2 p=1 + ReLU =============
// Torch weights (Cin, Cout, 4, 4). Block: 128 threads, out tile 16x16 x 32 co.
// Thread: 4 oy x 4 ox x 4 co = 64 accumulators. All edge masking at staging.
template<int Cin, int H, int W, int Cout>
__global__ void __launch_bounds__(128) convt4s2_lds(
    const float* __restrict__ x, const float* __restrict__ w,
    const float* __restrict__ bias, float* __restrict__ y)
{
    constexpr int OH = 2 * H, OW = 2 * W;
    constexpr int SPX = OW / 16, SPT = (OH / 16) * SPX;
    constexpr int NC = Cin / 8;
    constexpr int XEL = 8 * 10 * 12;            // 960 (incl col pad)
    constexpr int XIT = (XEL + 127) / 128;      // 8
    constexpr int WEL = 8 * 32 * 16;            // 4096
    constexpr int WIT = WEL / 128;              // 32

    __shared__ float xt[8][10][12];
    __shared__ float wt[8][16][36];

    int bid = blockIdx.x;
    int st  = bid % SPT; int t = bid / SPT;
    int cog = t % (Cout / 32);
    int n   = t / (Cout / 32);
    int oyb = (st / SPX) * 16, oxb = (st % SPX) * 16;
    int co0 = cog * 32;
    int ib = oyb / 2, jb = oxb / 2;

    int tid = threadIdx.x;
    int tx = tid & 3, ty = (tid >> 2) & 3, tc = tid >> 4;

    float acc[4][4][4];                          // [r][o][j]
#pragma unroll
    for (int o = 0; o < 4; ++o) {
        float b = bias[co0 + 4 * tc + o];
#pragma unroll
        for (int r = 0; r < 4; ++r)
#pragma unroll
            for (int j = 0; j < 4; ++j) acc[r][o][j] = b;
    }

    const float* xn = x + (size_t)n * Cin * H * W;
    float pfx[XIT];
    float pfw[WIT];

    auto load_chunk = [&](int c0) {
#pragma unroll
        for (int k = 0; k < XIT; ++k) {
            int i = tid + 128 * k;
            float v = 0.0f;
            if (i < XEL) {
                int lc  = i % 12;
                int r2  = i / 12;
                int lr  = r2 % 10;
                int icc = r2 / 10;
                int gr = ib - 1 + lr;
                int gc = jb - 1 + lc;
                if ((unsigned)gr < (unsigned)H && (unsigned)gc < (unsigned)W)
                    v = xn[((size_t)(c0 + icc) * H + gr) * W + gc];
            }
            pfx[k] = v;
        }
#pragma unroll
        for (int k = 0; k < WIT; ++k) {
            int i = tid + 128 * k;
            int kk  = i & 15;
            int col = (i >> 4) & 31;
            int icc = i >> 9;
            pfw[k] = w[((size_t)(c0 + icc) * Cout + co0 + col) * 16 + kk];
        }
    };
    auto store_chunk = [&]() {
#pragma unroll
        for (int k = 0; k < XIT; ++k) {
            int i = tid + 128 * k;
            if (i < XEL) ((float*)xt)[i] = pfx[k];
        }
#pragma unroll
        for (int k = 0; k < WIT; ++k) {
            int i = tid + 128 * k;
            int kk  = i & 15;
            int col = (i >> 4) & 31;
            int icc = i >> 9;
            wt[icc][kk][col] = pfw[k];
        }
    };

    load_chunk(0);
#pragma unroll 1
    for (int c = 0; c < NC; ++c) {
        __syncthreads();
        store_chunk();
        __syncthreads();
        if (c + 1 < NC) load_chunk((c + 1) * 8);

#pragma unroll 1
        for (int icc = 0; icc < 8; ++icc) {
            float xr[4][4];
#pragma unroll
            for (int q = 0; q < 4; ++q) {
                const float* rp = &xt[icc][2 * ty + q][2 * tx];
                float2 u = *(const float2*)rp;
                float2 v = *(const float2*)(rp + 2);
                xr[q][0] = u.x; xr[q][1] = u.y; xr[q][2] = v.x; xr[q][3] = v.y;
            }
            // pp=0: ky rows {1,3} serve r=0,2 ; pp=1: ky rows {0,2} serve r=1,3
#pragma unroll
            for (int pp = 0; pp < 2; ++pp) {
                const int kyA = 1 - pp, kyB = 3 - pp;
                float wA[4][4], wB[4][4];
#pragma unroll
                for (int kx = 0; kx < 4; ++kx) {
                    float4 ta = *(const float4*)&wt[icc][kyA * 4 + kx][4 * tc];
                    float4 tb = *(const float4*)&wt[icc][kyB * 4 + kx][4 * tc];
                    wA[kx][0] = ta.x; wA[kx][1] = ta.y; wA[kx][2] = ta.z; wA[kx][3] = ta.w;
                    wB[kx][0] = tb.x; wB[kx][1] = tb.y; wB[kx][2] = tb.z; wB[kx][3] = tb.w;
                }
#pragma unroll
                for (int rr = 0; rr < 2; ++rr) {
                    const int r  = pp + 2 * rr;
                    const int Ai = 1 + ((r + 1) >> 1);   // {1,2,2,3}
                    const float* a = xr[Ai];
                    const float* b = xr[Ai - 1];
#pragma unroll
                    for (int o = 0; o < 4; ++o) {
                        float s0 = acc[r][o][0], s1 = acc[r][o][1];
                        float s2 = acc[r][o][2], s3 = acc[r][o][3];
                        s0 = fmaf(a[1], wA[1][o], s0); s0 = fmaf(a[0], wA[3][o], s0);
                        s0 = fmaf(b[1], wB[1][o], s0); s0 = fmaf(b[0], wB[3][o], s0);
                        s1 = fmaf(a[2], wA[0][o], s1); s1 = fmaf(a[1], wA[2][o], s1);
                        s1 = fmaf(b[2], wB[0][o], s1); s1 = fmaf(b[1], wB[2][o], s1);
                        s2 = fmaf(a[2], wA[1][o], s2); s2 = fmaf(a[1], wA[3][o], s2);
                        s2 = fmaf(b[2], wB[1][o], s2); s2 = fmaf(b[1], wB[3][o], s2);
                        s3 = fmaf(a[3], wA[0][o], s3); s3 = fmaf(a[2], wA[2][o], s3);
                        s3 = fmaf(b[3], wB[0][o], s3); s3 = fmaf(b[2], wB[2][o], s3);
                        acc[r][o][0] = s0; acc[r][o][1] = s1;
                        acc[r][o][2] = s2; acc[r][o][3] = s3;
                    }
                }
            }
        }
    }

#pragma unroll
    for (int r = 0; r < 4; ++r) {
        int oy = oyb + 4 * ty + r;
#pragma unroll
        for (int o = 0; o < 4; ++o) {
            float* yr = y + (((size_t)n * Cout + co0 + 4 * tc + o) * OH + oy) * OW
                          + oxb + 4 * tx;
            float4 v;
            v.x = fmaxf(acc[r][o][0], 0.0f);
            v.y = fmaxf(acc[r][o][1], 0.0f);
            v.z = fmaxf(acc[r][o][2], 0.0f);
            v.w = fmaxf(acc[r][o][3], 0.0f);
            *(float4*)yr = v;
        }
    }
}

// ================= direct conv kernels (conv1 / g4 only) ===================
template<int Cin, int H, int W, int OCT, int UNR, bool INT>
__device__ __forceinline__ void conv_core(
    const float* __restrict__ xn, const float* __restrict__ wbase,
    int iy0, int ix0, float (&acc)[OCT][4])
{
#pragma unroll UNR
    for (int ic = 0; ic < Cin; ++ic) {
        const float* xc = xn + (size_t)ic * (H * W);
        float xv[4][10];
#pragma unroll
        for (int ky = 0; ky < 4; ++ky) {
            int iy = iy0 + ky;
            if (INT) {
                const float* xr = xc + (size_t)iy * W;
#pragma unroll
                for (int j = 0; j < 10; ++j) xv[ky][j] = xr[ix0 + j];
            } else {
                bool rv = ((unsigned)iy < (unsigned)H);
                const float* xr = xc + (size_t)(rv ? iy : 0) * W;
#pragma unroll
                for (int j = 0; j < 10; ++j) {
                    int ix = ix0 + j;
                    bool cv = rv && ((unsigned)ix < (unsigned)W);
                    xv[ky][j] = cv ? xr[cv ? ix : 0] : 0.0f;
                }
            }
        }
#pragma unroll
        for (int o = 0; o < OCT; ++o) {
            const float* wr = wbase + (size_t)o * (Cin * 16) + ic * 16;
#pragma unroll
            for (int ky = 0; ky < 4; ++ky) {
                float w0 = wr[ky * 4 + 0], w1 = wr[ky * 4 + 1];
                float w2 = wr[ky * 4 + 2], w3 = wr[ky * 4 + 3];
#pragma unroll
                for (int j = 0; j < 4; ++j) {
                    acc[o][j] = fmaf(xv[ky][2 * j],     w0, acc[o][j]);
                    acc[o][j] = fmaf(xv[ky][2 * j + 1], w1, acc[o][j]);
                    acc[o][j] = fmaf(xv[ky][2 * j + 2], w2, acc[o][j]);
                    acc[o][j] = fmaf(xv[ky][2 * j + 3], w3, acc[o][j]);
                }
            }
        }
    }
}

template<int Cin, int H, int W, int Cout, int OCT, int UNR>
__global__ void __launch_bounds__(256) conv4s2_k(
    const float* __restrict__ x, const float* __restrict__ w,
    const float* __restrict__ bias, float* __restrict__ y)
{
    constexpr int OH = H / 2, OW = W / 2, OWq = OW / 4;
    int id = blockIdx.x * 256 + threadIdx.x;
    int ox4 = id % OWq; int t = id / OWq;
    int oy  = t % OH;   t /= OH;
    int ocg = t % (Cout / OCT);
    int n   = t / (Cout / OCT);
    int oc0 = __builtin_amdgcn_readfirstlane(ocg * OCT);
    n       = __builtin_amdgcn_readfirstlane(n);

    float acc[OCT][4];
#pragma unroll
    for (int o = 0; o < OCT; ++o) {
        float b = bias[oc0 + o];
#pragma unroll
        for (int j = 0; j < 4; ++j) acc[o][j] = b;
    }

    const float* xn    = x + (size_t)n * Cin * H * W;
    const float* wbase = w + (size_t)oc0 * Cin * 16;
    int iy0 = 2 * oy - 1;
    int ix0 = 8 * ox4 - 1;

    bool interior = (oy >= 1) && (oy <= OH - 2) && (ox4 >= 1) && (ox4 <= OWq - 2);
    if (interior) conv_core<Cin, H, W, OCT, UNR, true >(xn, wbase, iy0, ix0, acc);
    else          conv_core<Cin, H, W, OCT, UNR, false>(xn, wbase, iy0, ix0, acc);

    int ox0 = ox4 * 4;
#pragma unroll
    for (int o = 0; o < OCT; ++o) {
        float* yr = y + (((size_t)n * Cout + oc0 + o) * OH + oy) * OW + ox0;
#pragma unroll
        for (int j = 0; j < 4; ++j) yr[j] = fmaxf(acc[o][j], 0.0f);
    }
}

template<int Cin, int H, int W, int Cout, int COT, int ACT, int UNR>
__global__ void __launch_bounds__(256) convt4s2_k(
    const float* __restrict__ x, const float* __restrict__ w,
    const float* __restrict__ bias, float* __restrict__ y)
{
    constexpr int OH = 2 * H, OW = 2 * W, OWq = OW / 4;
    int id = blockIdx.x * 256 + threadIdx.x;
    int ox4 = id % OWq; int t = id / OWq;
    int oy  = t % OH;   t /= OH;
    int cog = t % (Cout / COT);
    int n   = t / (Cout / COT);
    int co0 = __builtin_amdgcn_readfirstlane(cog * COT);
    n       = __builtin_amdgcn_readfirstlane(n);

    int p   = (oy + 1) & 1;
    int iyA = (oy + 1 - p) >> 1;
    int iyB = iyA - 1;
    bool vA = (iyA < H);
    bool vB = (iyB >= 0);
    int iyAc = vA ? iyA : 0, iyBc = vB ? iyB : 0;

    int t0 = 2 * ox4;
    bool c0 = (t0 - 1 >= 0);
    bool c3 = (t0 + 2 <= W - 1);
    int j0 = c0 ? t0 - 1 : 0;
    int j3 = c3 ? t0 + 2 : 0;

    float acc[COT][4];
#pragma unroll
    for (int o = 0; o < COT; ++o) {
        float b = bias[co0 + o];
#pragma unroll
        for (int j = 0; j < 4; ++j) acc[o][j] = b;
    }

    const float* xn = x + (size_t)n * Cin * H * W;

#pragma unroll UNR
    for (int ci = 0; ci < Cin; ++ci) {
        const float* xc  = xn + (size_t)ci * (H * W);
        const float* xrA = xc + (size_t)iyAc * W;
        const float* xrB = xc + (size_t)iyBc * W;
        float a0 = (vA && c0) ? xrA[j0]     : 0.0f;
        float a1 =  vA        ? xrA[t0]     : 0.0f;
        float a2 =  vA        ? xrA[t0 + 1] : 0.0f;
        float a3 = (vA && c3) ? xrA[j3]     : 0.0f;
        float b0 = (vB && c0) ? xrB[j0]     : 0.0f;
        float b1 =  vB        ? xrB[t0]     : 0.0f;
        float b2 =  vB        ? xrB[t0 + 1] : 0.0f;
        float b3 = (vB && c3) ? xrB[j3]     : 0.0f;

        const float* wci = w + ((size_t)ci * Cout + co0) * 16;
#pragma unroll
        for (int o = 0; o < COT; ++o) {
            const float* wr = wci + (size_t)o * 16;
            float wA0 = wr[p * 4 + 0], wA1 = wr[p * 4 + 1];
            float wA2 = wr[p * 4 + 2], wA3 = wr[p * 4 + 3];
            float wB0 = wr[(p + 2) * 4 + 0], wB1 = wr[(p + 2) * 4 + 1];
            float wB2 = wr[(p + 2) * 4 + 2], wB3 = wr[(p + 2) * 4 + 3];
            acc[o][0] = fmaf(a1, wA1, acc[o][0]); acc[o][0] = fmaf(a0, wA3, acc[o][0]);
            acc[o][0] = fmaf(b1, wB1, acc[o][0]); acc[o][0] = fmaf(b0, wB3, acc[o][0]);
            acc[o][1] = fmaf(a2, wA0, acc[o][1]); acc[o][1] = fmaf(a1, wA2, acc[o][1]);
            acc[o][1] = fmaf(b2, wB0, acc[o][1]); acc[o][1] = fmaf(b1, wB2, acc[o][1]);
            acc[o][2] = fmaf(a2, wA1, acc[o][2]); acc[o][2] = fmaf(a1, wA3, acc[o][2]);
            acc[o][2] = fmaf(b2, wB1, acc[o][2]); acc[o][2] = fmaf(b1, wB3, acc[o][2]);
            acc[o][3] = fmaf(a3, wA0, acc[o][3]); acc[o][3] = fmaf(a2, wA2, acc[o][3]);
            acc[o][3] = fmaf(b3, wB0, acc[o][3]); acc[o][3] = fmaf(b2, wB2, acc[o][3]);
        }
    }

    int ox0 = ox4 * 4;
#pragma unroll
    for (int o = 0; o < COT; ++o) {
        float* yr = y + (((size_t)n * Cout + co0 + o) * OH + oy) * OW + ox0;
#pragma unroll
        for (int j = 0; j < 4; ++j) {
            float v = acc[o][j];
            yr[j] = (ACT == 0) ? fmaxf(v, 0.0f) : tanhf(v);
        }
    }
}

// =============================== quantizer =================================
__global__ void __launch_bounds__(256) embed_norms(
    const float* __restrict__ embed, float* __restrict__ norms)
{
    int c = blockIdx.x * 256 + threadIdx.x;
    const float* e = embed + (size_t)c * 512;
    float s = 0.0f;
    for (int k = 0; k < 512; ++k) s = fmaf(e[k], e[k], s);
    norms[c] = s;
}

__global__ void __launch_bounds__(256) vq_argmin8(
    const float* __restrict__ z, const float* __restrict__ embed,
    const float* __restrict__ norms, int* __restrict__ out)
{
    int row0 = blockIdx.x * 8;
    int n    = row0 >> 8;
    int yx0  = row0 & 255;

    __shared__ float zr[8 * 512];
    const float* zn = z + ((size_t)n * 512) * 256;
    for (int i = threadIdx.x; i < 8 * 512; i += 256) {
        int r = i >> 9, c = i & 511;
        zr[i] = zn[((size_t)c << 8) + yx0 + r];
    }
    __syncthreads();

    float best[8]; int bi[8];
#pragma unroll
    for (int r = 0; r < 8; ++r) { best[r] = 3.4e38f; bi[r] = 0; }

#pragma unroll
    for (int rep = 0; rep < 4; ++rep) {
        int code = rep * 256 + threadIdx.x;
        const float4* e4 = (const float4*)(embed + (size_t)code * 512);
        float dot[8];
#pragma unroll
        for (int r = 0; r < 8; ++r) dot[r] = 0.0f;
        for (int k4 = 0; k4 < 128; ++k4) {
            float4 e = e4[k4];
#pragma unroll
            for (int r = 0; r < 8; ++r) {
                const float4 zz = *(const float4*)&zr[r * 512 + k4 * 4];
                dot[r] = fmaf(e.x, zz.x, dot[r]);
                dot[r] = fmaf(e.y, zz.y, dot[r]);
                dot[r] = fmaf(e.z, zz.z, dot[r]);
                dot[r] = fmaf(e.w, zz.w, dot[r]);
            }
        }
        float nb = norms[code];
#pragma unroll
        for (int r = 0; r < 8; ++r) {
            float d = nb - 2.0f * dot[r];
            if (d < best[r]) { best[r] = d; bi[r] = code; }
        }
    }

    __shared__ float rbd[8 * 256];
    __shared__ int   rbi[8 * 256];
#pragma unroll
    for (int r = 0; r < 8; ++r) {
        rbd[r * 256 + threadIdx.x] = best[r];
        rbi[r * 256 + threadIdx.x] = bi[r];
    }
    __syncthreads();
    for (int s = 128; s > 0; s >>= 1) {
        if ((int)threadIdx.x < s) {
#pragma unroll
            for (int r = 0; r < 8; ++r) {
                int i0 = r * 256 + threadIdx.x;
                float od = rbd[i0 + s]; int oi = rbi[i0 + s];
                float md = rbd[i0];     int mi = rbi[i0];
                if (od < md || (od == md && oi < mi)) { rbd[i0] = od; rbi[i0] = oi; }
            }
        }
        __syncthreads();
    }
    if (threadIdx.x < 8) out[row0 + threadIdx.x] = rbi[threadIdx.x * 256];
}

__global__ void __launch_bounds__(256) vq_gather(
    const int* __restrict__ vidx, const float* __restrict__ embed,
    float* __restrict__ zq)
{
    int i = blockIdx.x * 256 + threadIdx.x;
    int yx = i & 255;
    int t  = i >> 8;
    int c  = t & 511;
    int n  = t >> 9;
    int row = (n << 8) + yx;
    zq[i] = embed[(size_t)vidx[row] * 512 + c];
}

// ================================ launch ===================================
extern "C" void kernel_launch(void* const* d_in, const int* in_sizes, int n_in,
                              void* d_out, int out_size, void* d_ws, size_t ws_size,
                              hipStream_t stream)
{
    (void)in_sizes; (void)n_in; (void)out_size; (void)ws_size;
    const float* x     = (const float*)d_in[0];
    const float* ew1   = (const float*)d_in[1];
    const float* eb1   = (const float*)d_in[2];
    const float* ew2   = (const float*)d_in[3];
    const float* eb2   = (const float*)d_in[4];
    const float* ew3   = (const float*)d_in[5];
    const float* eb3   = (const float*)d_in[6];
    const float* ew4   = (const float*)d_in[7];
    const float* eb4   = (const float*)d_in[8];
    const float* dw1   = (const float*)d_in[9];
    const float* db1   = (const float*)d_in[10];
    const float* dw2   = (const float*)d_in[11];
    const float* db2   = (const float*)d_in[12];
    const float* dw3   = (const float*)d_in[13];
    const float* db3   = (const float*)d_in[14];
    const float* dw4   = (const float*)d_in[15];
    const float* db4   = (const float*)d_in[16];
    const float* embed = (const float*)d_in[17];
    float* out = (float*)d_out;

    float* A     = (float*)d_ws;                 // 128 MiB
    float* B     = A + 33554432;                 // 64 MiB
    int*   vidx  = (int*)(B + 16777216);
    float* norms = (float*)(vidx + 8192);

    dim3 b256(256), b128(128);

    // ---- encoder ----
    conv4s2_k<3, 256, 256, 64, 4, 3><<<dim3(8192), b256, 0, stream>>>(
        x, ew1, eb1, A);                                   // h1 -> A
    conv4s2_lds<64, 128, 128, 128><<<dim3(32 * 4 * 16), b256, 0, stream>>>(
        A, ew2, eb2, B);                                   // h2 -> B
    conv4s2_lds<128, 64, 64, 256><<<dim3(32 * 8 * 4), b256, 0, stream>>>(
        B, ew3, eb3, A);                                   // h3 -> A
    conv4s2_lds<256, 32, 32, 512><<<dim3(32 * 16 * 1), b256, 0, stream>>>(
        A, ew4, eb4, B);                                   // z  -> B

    // ---- quantizer ----
    embed_norms<<<dim3(4), b256, 0, stream>>>(embed, norms);
    vq_argmin8<<<dim3(1024), b256, 0, stream>>>(B, embed, norms, vidx);
    vq_gather<<<dim3(16384), b256, 0, stream>>>(vidx, embed, A);   // zq -> A

    // ---- decoder ----
    convt4s2_lds<512, 16, 16, 128><<<dim3(32 * 4 * 4), b128, 0, stream>>>(
        A, dw1, db1, B);                                   // g1 -> B
    convt4s2_lds<128, 32, 32, 64><<<dim3(32 * 2 * 16), b128, 0, stream>>>(
        B, dw2, db2, A);                                   // g2 -> A
    convt4s2_lds<64, 64, 64, 32><<<dim3(32 * 1 * 64), b128, 0, stream>>>(
        A, dw3, db3, B);                                   // g3 -> B
    convt4s2_k<32, 128, 128, 3, 3, 1, 2><<<dim3(2048), b256, 0, stream>>>(
        B, dw4, db4, out);                                 // out (tanh)
}

// Round 5
// 3315.598 us; speedup vs baseline: 11.7031x; 1.1158x over previous
//
#include <hip/hip_runtime.h>
#include <math.h>

// ---------------------------------------------------------------------------
// VQ-VAE forward, fp32. Round 5: LDS bank-conflict fixes.
//  - xs (conv input tile): XOR swizzle of 4-float blocks by (row>>2)&3.
//  - ws/wt (weights): ocl-fastest staging lane map -> 2-way (free) writes.
//  - convT: 4-channel chunks (smaller prefetch arrays), wt stride 32.
// ---------------------------------------------------------------------------

// ======================= LDS-staged Conv2d k=4 s=2 p=1 + ReLU ==============
// Block: 256 threads, output tile 16x16 spatial x 32 oc.
// Thread: 2 oy x 4 ox x 4 oc = 32 accumulators.
template<int Cin, int H, int W, int Cout>
__global__ void __launch_bounds__(256) conv4s2_lds(
    const float* __restrict__ x, const float* __restrict__ w,
    const float* __restrict__ bias, float* __restrict__ y)
{
    constexpr int OH = H / 2, OW = W / 2;
    constexpr int SPX = OW / 16, SPT = (OH / 16) * SPX;
    constexpr int NC = Cin / 4;
    constexpr int XEL = 4 * 34 * 36;
    constexpr int XIT = (XEL + 255) / 256;      // 20
    constexpr int WEL = 4 * 16 * 32;
    constexpr int WIT = WEL / 256;              // 8

    __shared__ float xs[4][34][36];             // col-blocks XOR-swizzled
    __shared__ float ws[4][16][36];             // [icc][kk][ocl] (pad 36)

    int bid = blockIdx.x;
    int st  = bid % SPT; int t = bid / SPT;
    int ocg = t % (Cout / 32);
    int n   = t / (Cout / 32);
    int oyb = (st / SPX) * 16, oxb = (st % SPX) * 16;
    int oc0 = ocg * 32;

    int tid = threadIdx.x;
    int tx = tid & 3, ty = (tid >> 2) & 7, tc = tid >> 5;

    float acc[2][4][4];
#pragma unroll
    for (int o = 0; o < 4; ++o) {
        float b = bias[oc0 + 4 * tc + o];
#pragma unroll
        for (int r = 0; r < 2; ++r)
#pragma unroll
            for (int j = 0; j < 4; ++j) acc[r][o][j] = b;
    }

    // Precomputed swizzled read offsets (floats) for e4 = 0 / 1.
    int u0 = ty & 3, u1 = (ty + 1) & 3;
    int cA0_0 = 4 * ((2 * tx)     ^ u0);
    int cA0_1 = 4 * ((2 * tx + 1) ^ u0);
    int cA0_2 = (tx == 3) ? 32 : 4 * ((2 * tx + 2) ^ u0);
    int cA1_0 = 4 * ((2 * tx)     ^ u1);
    int cA1_1 = 4 * ((2 * tx + 1) ^ u1);
    int cA1_2 = (tx == 3) ? 32 : 4 * ((2 * tx + 2) ^ u1);

    const float* xn = x + (size_t)n * Cin * H * W;
    float pfx[XIT];
    float pfw[WIT];

    auto load_chunk = [&](int c0) {
#pragma unroll
        for (int k = 0; k < XIT; ++k) {
            int i = tid + 256 * k;
            float v = 0.0f;
            if (i < XEL) {
                int lc  = i % 36;
                int r2  = i / 36;
                int lr  = r2 % 34;
                int icc = r2 / 34;
                int gr = 2 * oyb - 1 + lr;
                int gc = 2 * oxb - 1 + lc;
                if ((unsigned)gr < (unsigned)H && (unsigned)gc < (unsigned)W)
                    v = xn[((size_t)(c0 + icc) * H + gr) * W + gc];
            }
            pfx[k] = v;
        }
#pragma unroll
        for (int k = 0; k < WIT; ++k) {
            int i = tid + 256 * k;
            int ocl = i & 31;
            int kk  = (i >> 5) & 15;
            int icc = i >> 9;
            pfw[k] = w[((size_t)(oc0 + ocl) * Cin + c0 + icc) * 16 + kk];
        }
    };
    auto store_chunk = [&]() {
        float* xf = (float*)xs;
#pragma unroll
        for (int k = 0; k < XIT; ++k) {
            int i = tid + 256 * k;
            if (i < XEL) {
                int lc  = i % 36;
                int r2  = i / 36;
                int lr  = r2 % 34;
                int icc = r2 / 34;
                int pb  = lc >> 2, wi = lc & 3;
                int ppb = (pb < 8) ? (pb ^ ((lr >> 2) & 3)) : 8;
                xf[icc * (34 * 36) + lr * 36 + ppb * 4 + wi] = pfx[k];
            }
        }
#pragma unroll
        for (int k = 0; k < WIT; ++k) {
            int i = tid + 256 * k;
            int ocl = i & 31;
            int kk  = (i >> 5) & 15;
            int icc = i >> 9;
            ws[icc][kk][ocl] = pfw[k];          // banks: ocl+4*kk -> 2-way, free
        }
    };

    load_chunk(0);
#pragma unroll 1
    for (int c = 0; c < NC; ++c) {
        __syncthreads();
        store_chunk();
        __syncthreads();
        if (c + 1 < NC) load_chunk((c + 1) * 4);

#pragma unroll 1
        for (int icc = 0; icc < 4; ++icc) {
#pragma unroll
            for (int ky = 0; ky < 4; ++ky) {
                float4 wv[4];
#pragma unroll
                for (int kx = 0; kx < 4; ++kx)
                    wv[kx] = *(const float4*)&ws[icc][ky * 4 + kx][4 * tc];
#pragma unroll
                for (int r = 0; r < 2; ++r) {
                    const int e = 2 * r + ky;            // compile-time
                    const float* row = &xs[icc][4 * ty + e][0];
                    float4 a, b; float2 cc;
                    if (e >= 4) {
                        a  = *(const float4*)(row + cA1_0);
                        b  = *(const float4*)(row + cA1_1);
                        cc = *(const float2*)(row + cA1_2);
                    } else {
                        a  = *(const float4*)(row + cA0_0);
                        b  = *(const float4*)(row + cA0_1);
                        cc = *(const float2*)(row + cA0_2);
                    }
                    float xv[10] = {a.x, a.y, a.z, a.w,
                                    b.x, b.y, b.z, b.w, cc.x, cc.y};
#pragma unroll
                    for (int j = 0; j < 4; ++j)
#pragma unroll
                        for (int kx = 0; kx < 4; ++kx) {
                            float xval = xv[2 * j + kx];
                            acc[r][0][j] = fmaf(xval, wv[kx].x, acc[r][0][j]);
                            acc[r][1][j] = fmaf(xval, wv[kx].y, acc[r][1][j]);
                            acc[r][2][j] = fmaf(xval, wv[kx].z, acc[r][2][j]);
                            acc[r][3][j] = fmaf(xval, wv[kx].w, acc[r][3][j]);
                        }
                }
            }
        }
    }

#pragma unroll
    for (int r = 0; r < 2; ++r) {
        int oy = oyb + 2 * ty + r;
#pragma unroll
        for (int o = 0; o < 4; ++o) {
            float* yr = y + (((size_t)n * Cout + oc0 + 4 * tc + o) * OH + oy) * OW
                          + oxb + 4 * tx;
            float4 v;
            v.x = fmaxf(acc[r][o][0], 0.0f);
            v.y = fmaxf(acc[r][o][1], 0.0f);
            v.z = fmaxf(acc[r][o][2], 0.0f);
            v.w = fmaxf(acc[r][o][3], 0.0f);
            *(float4*)yr = v;
        }
    }
}

// =============== LDS-staged ConvTranspose2d k=4 s=2 p=1 + ReLU =============
// Torch weights (Cin, Cout, 4, 4). Block: 128 threads, out tile 16x16 x 32 co.
// Thread: 4 oy x 4 ox x 4 co = 64 accumulators. 4-channel chunks.
template<int Cin, int H, int W, int Cout>
__global__ void __launch_bounds__(128) convt4s2_lds(
    const float* __restrict__ x, const float* __restrict__ w,
    const float* __restrict__ bias, float* __restrict__ y)
{
    constexpr int OH = 2 * H, OW = 2 * W;
    constexpr int SPX = OW / 16, SPT = (OH / 16) * SPX;
    constexpr int NC = Cin / 4;
    constexpr int XEL = 4 * 10 * 12;            // 480
    constexpr int XIT = (XEL + 127) / 128;      // 4
    constexpr int WEL = 4 * 32 * 16;            // 2048
    constexpr int WIT = WEL / 128;              // 16

    __shared__ float xt[4][10][12];
    __shared__ float wt[4][16][32];             // [icc][kk][col], stride 32

    int bid = blockIdx.x;
    int st  = bid % SPT; int t = bid / SPT;
    int cog = t % (Cout / 32);
    int n   = t / (Cout / 32);
    int oyb = (st / SPX) * 16, oxb = (st % SPX) * 16;
    int co0 = cog * 32;
    int ib = oyb / 2, jb = oxb / 2;

    int tid = threadIdx.x;
    int tx = tid & 3, ty = (tid >> 2) & 3, tc = tid >> 4;

    float acc[4][4][4];
#pragma unroll
    for (int o = 0; o < 4; ++o) {
        float b = bias[co0 + 4 * tc + o];
#pragma unroll
        for (int r = 0; r < 4; ++r)
#pragma unroll
            for (int j = 0; j < 4; ++j) acc[r][o][j] = b;
    }

    const float* xn = x + (size_t)n * Cin * H * W;
    float pfx[XIT];
    float pfw[WIT];

    auto load_chunk = [&](int c0) {
#pragma unroll
        for (int k = 0; k < XIT; ++k) {
            int i = tid + 128 * k;
            float v = 0.0f;
            if (i < XEL) {
                int lc  = i % 12;
                int r2  = i / 12;
                int lr  = r2 % 10;
                int icc = r2 / 10;
                int gr = ib - 1 + lr;
                int gc = jb - 1 + lc;
                if ((unsigned)gr < (unsigned)H && (unsigned)gc < (unsigned)W)
                    v = xn[((size_t)(c0 + icc) * H + gr) * W + gc];
            }
            pfx[k] = v;
        }
#pragma unroll
        for (int k = 0; k < WIT; ++k) {
            int i = tid + 128 * k;
            int col = i & 31;
            int kk  = (i >> 5) & 15;
            int icc = i >> 9;
            pfw[k] = w[((size_t)(c0 + icc) * Cout + co0 + col) * 16 + kk];
        }
    };
    auto store_chunk = [&]() {
#pragma unroll
        for (int k = 0; k < XIT; ++k) {
            int i = tid + 128 * k;
            if (i < XEL) ((float*)xt)[i] = pfx[k];
        }
#pragma unroll
        for (int k = 0; k < WIT; ++k) {
            int i = tid + 128 * k;
            int col = i & 31;
            int kk  = (i >> 5) & 15;
            int icc = i >> 9;
            wt[icc][kk][col] = pfw[k];          // banks = col -> 2-way, free
        }
    };

    load_chunk(0);
#pragma unroll 1
    for (int c = 0; c < NC; ++c) {
        __syncthreads();
        store_chunk();
        __syncthreads();
        if (c + 1 < NC) load_chunk((c + 1) * 4);

#pragma unroll 1
        for (int icc = 0; icc < 4; ++icc) {
            float xr[4][4];
#pragma unroll
            for (int q = 0; q < 4; ++q) {
                const float* rp = &xt[icc][2 * ty + q][2 * tx];
                float2 u = *(const float2*)rp;
                float2 v = *(const float2*)(rp + 2);
                xr[q][0] = u.x; xr[q][1] = u.y; xr[q][2] = v.x; xr[q][3] = v.y;
            }
#pragma unroll
            for (int pp = 0; pp < 2; ++pp) {
                const int kyA = 1 - pp, kyB = 3 - pp;
                float wA[4][4], wB[4][4];
#pragma unroll
                for (int kx = 0; kx < 4; ++kx) {
                    float4 ta = *(const float4*)&wt[icc][kyA * 4 + kx][4 * tc];
                    float4 tb = *(const float4*)&wt[icc][kyB * 4 + kx][4 * tc];
                    wA[kx][0] = ta.x; wA[kx][1] = ta.y; wA[kx][2] = ta.z; wA[kx][3] = ta.w;
                    wB[kx][0] = tb.x; wB[kx][1] = tb.y; wB[kx][2] = tb.z; wB[kx][3] = tb.w;
                }
#pragma unroll
                for (int rr = 0; rr < 2; ++rr) {
                    const int r  = pp + 2 * rr;
                    const int Ai = 1 + ((r + 1) >> 1);
                    const float* a = xr[Ai];
                    const float* b = xr[Ai - 1];
#pragma unroll
                    for (int o = 0; o < 4; ++o) {
                        float s0 = acc[r][o][0], s1 = acc[r][o][1];
                        float s2 = acc[r][o][2], s3 = acc[r][o][3];
                        s0 = fmaf(a[1], wA[1][o], s0); s0 = fmaf(a[0], wA[3][o], s0);
                        s0 = fmaf(b[1], wB[1][o], s0); s0 = fmaf(b[0], wB[3][o], s0);
                        s1 = fmaf(a[2], wA[0][o], s1); s1 = fmaf(a[1], wA[2][o], s1);
                        s1 = fmaf(b[2], wB[0][o], s1); s1 = fmaf(b[1], wB[2][o], s1);
                        s2 = fmaf(a[2], wA[1][o], s2); s2 = fmaf(a[1], wA[3][o], s2);
                        s2 = fmaf(b[2], wB[1][o], s2); s2 = fmaf(b[1], wB[3][o], s2);
                        s3 = fmaf(a[3], wA[0][o], s3); s3 = fmaf(a[2], wA[2][o], s3);
                        s3 = fmaf(b[3], wB[0][o], s3); s3 = fmaf(b[2], wB[2][o], s3);
                        acc[r][o][0] = s0; acc[r][o][1] = s1;
                        acc[r][o][2] = s2; acc[r][o][3] = s3;
                    }
                }
            }
        }
    }

#pragma unroll
    for (int r = 0; r < 4; ++r) {
        int oy = oyb + 4 * ty + r;
#pragma unroll
        for (int o = 0; o < 4; ++o) {
            float* yr = y + (((size_t)n * Cout + co0 + 4 * tc + o) * OH + oy) * OW
                          + oxb + 4 * tx;
            float4 v;
            v.x = fmaxf(acc[r][o][0], 0.0f);
            v.y = fmaxf(acc[r][o][1], 0.0f);
            v.z = fmaxf(acc[r][o][2], 0.0f);
            v.w = fmaxf(acc[r][o][3], 0.0f);
            *(float4*)yr = v;
        }
    }
}

// ================= direct conv kernels (conv1 / g4 only) ===================
template<int Cin, int H, int W, int OCT, int UNR, bool INT>
__device__ __forceinline__ void conv_core(
    const float* __restrict__ xn, const float* __restrict__ wbase,
    int iy0, int ix0, float (&acc)[OCT][4])
{
#pragma unroll UNR
    for (int ic = 0; ic < Cin; ++ic) {
        const float* xc = xn + (size_t)ic * (H * W);
        float xv[4][10];
#pragma unroll
        for (int ky = 0; ky < 4; ++ky) {
            int iy = iy0 + ky;
            if (INT) {
                const float* xr = xc + (size_t)iy * W;
#pragma unroll
                for (int j = 0; j < 10; ++j) xv[ky][j] = xr[ix0 + j];
            } else {
                bool rv = ((unsigned)iy < (unsigned)H);
                const float* xr = xc + (size_t)(rv ? iy : 0) * W;
#pragma unroll
                for (int j = 0; j < 10; ++j) {
                    int ix = ix0 + j;
                    bool cv = rv && ((unsigned)ix < (unsigned)W);
                    xv[ky][j] = cv ? xr[cv ? ix : 0] : 0.0f;
                }
            }
        }
#pragma unroll
        for (int o = 0; o < OCT; ++o) {
            const float* wr = wbase + (size_t)o * (Cin * 16) + ic * 16;
#pragma unroll
            for (int ky = 0; ky < 4; ++ky) {
                float w0 = wr[ky * 4 + 0], w1 = wr[ky * 4 + 1];
                float w2 = wr[ky * 4 + 2], w3 = wr[ky * 4 + 3];
#pragma unroll
                for (int j = 0; j < 4; ++j) {
                    acc[o][j] = fmaf(xv[ky][2 * j],     w0, acc[o][j]);
                    acc[o][j] = fmaf(xv[ky][2 * j + 1], w1, acc[o][j]);
                    acc[o][j] = fmaf(xv[ky][2 * j + 2], w2, acc[o][j]);
                    acc[o][j] = fmaf(xv[ky][2 * j + 3], w3, acc[o][j]);
                }
            }
        }
    }
}

template<int Cin, int H, int W, int Cout, int OCT, int UNR>
__global__ void __launch_bounds__(256) conv4s2_k(
    const float* __restrict__ x, const float* __restrict__ w,
    const float* __restrict__ bias, float* __restrict__ y)
{
    constexpr int OH = H / 2, OW = W / 2, OWq = OW / 4;
    int id = blockIdx.x * 256 + threadIdx.x;
    int ox4 = id % OWq; int t = id / OWq;
    int oy  = t % OH;   t /= OH;
    int ocg = t % (Cout / OCT);
    int n   = t / (Cout / OCT);
    int oc0 = __builtin_amdgcn_readfirstlane(ocg * OCT);
    n       = __builtin_amdgcn_readfirstlane(n);

    float acc[OCT][4];
#pragma unroll
    for (int o = 0; o < OCT; ++o) {
        float b = bias[oc0 + o];
#pragma unroll
        for (int j = 0; j < 4; ++j) acc[o][j] = b;
    }

    const float* xn    = x + (size_t)n * Cin * H * W;
    const float* wbase = w + (size_t)oc0 * Cin * 16;
    int iy0 = 2 * oy - 1;
    int ix0 = 8 * ox4 - 1;

    bool interior = (oy >= 1) && (oy <= OH - 2) && (ox4 >= 1) && (ox4 <= OWq - 2);
    if (interior) conv_core<Cin, H, W, OCT, UNR, true >(xn, wbase, iy0, ix0, acc);
    else          conv_core<Cin, H, W, OCT, UNR, false>(xn, wbase, iy0, ix0, acc);

    int ox0 = ox4 * 4;
#pragma unroll
    for (int o = 0; o < OCT; ++o) {
        float* yr = y + (((size_t)n * Cout + oc0 + o) * OH + oy) * OW + ox0;
#pragma unroll
        for (int j = 0; j < 4; ++j) yr[j] = fmaxf(acc[o][j], 0.0f);
    }
}

template<int Cin, int H, int W, int Cout, int COT, int ACT, int UNR>
__global__ void __launch_bounds__(256) convt4s2_k(
    const float* __restrict__ x, const float* __restrict__ w,
    const float* __restrict__ bias, float* __restrict__ y)
{
    constexpr int OH = 2 * H, OW = 2 * W, OWq = OW / 4;
    int id = blockIdx.x * 256 + threadIdx.x;
    int ox4 = id % OWq; int t = id / OWq;
    int oy  = t % OH;   t /= OH;
    int cog = t % (Cout / COT);
    int n   = t / (Cout / COT);
    int co0 = __builtin_amdgcn_readfirstlane(cog * COT);
    n       = __builtin_amdgcn_readfirstlane(n);

    int p   = (oy + 1) & 1;
    int iyA = (oy + 1 - p) >> 1;
    int iyB = iyA - 1;
    bool vA = (iyA < H);
    bool vB = (iyB >= 0);
    int iyAc = vA ? iyA : 0, iyBc = vB ? iyB : 0;

    int t0 = 2 * ox4;
    bool c0 = (t0 - 1 >= 0);
    bool c3 = (t0 + 2 <= W - 1);
    int j0 = c0 ? t0 - 1 : 0;
    int j3 = c3 ? t0 + 2 : 0;

    float acc[COT][4];
#pragma unroll
    for (int o = 0; o < COT; ++o) {
        float b = bias[co0 + o];
#pragma unroll
        for (int j = 0; j < 4; ++j) acc[o][j] = b;
    }

    const float* xn = x + (size_t)n * Cin * H * W;

#pragma unroll UNR
    for (int ci = 0; ci < Cin; ++ci) {
        const float* xc  = xn + (size_t)ci * (H * W);
        const float* xrA = xc + (size_t)iyAc * W;
        const float* xrB = xc + (size_t)iyBc * W;
        float a0 = (vA && c0) ? xrA[j0]     : 0.0f;
        float a1 =  vA        ? xrA[t0]     : 0.0f;
        float a2 =  vA        ? xrA[t0 + 1] : 0.0f;
        float a3 = (vA && c3) ? xrA[j3]     : 0.0f;
        float b0 = (vB && c0) ? xrB[j0]     : 0.0f;
        float b1 =  vB        ? xrB[t0]     : 0.0f;
        float b2 =  vB        ? xrB[t0 + 1] : 0.0f;
        float b3 = (vB && c3) ? xrB[j3]     : 0.0f;

        const float* wci = w + ((size_t)ci * Cout + co0) * 16;
#pragma unroll
        for (int o = 0; o < COT; ++o) {
            const float* wr = wci + (size_t)o * 16;
            float wA0 = wr[p * 4 + 0], wA1 = wr[p * 4 + 1];
            float wA2 = wr[p * 4 + 2], wA3 = wr[p * 4 + 3];
            float wB0 = wr[(p + 2) * 4 + 0], wB1 = wr[(p + 2) * 4 + 1];
            float wB2 = wr[(p + 2) * 4 + 2], wB3 = wr[(p + 2) * 4 + 3];
            acc[o][0] = fmaf(a1, wA1, acc[o][0]); acc[o][0] = fmaf(a0, wA3, acc[o][0]);
            acc[o][0] = fmaf(b1, wB1, acc[o][0]); acc[o][0] = fmaf(b0, wB3, acc[o][0]);
            acc[o][1] = fmaf(a2, wA0, acc[o][1]); acc[o][1] = fmaf(a1, wA2, acc[o][1]);
            acc[o][1] = fmaf(b2, wB0, acc[o][1]); acc[o][1] = fmaf(b1, wB2, acc[o][1]);
            acc[o][2] = fmaf(a2, wA1, acc[o][2]); acc[o][2] = fmaf(a1, wA3, acc[o][2]);
            acc[o][2] = fmaf(b2, wB1, acc[o][2]); acc[o][2] = fmaf(b1, wB3, acc[o][2]);
            acc[o][3] = fmaf(a3, wA0, acc[o][3]); acc[o][3] = fmaf(a2, wA2, acc[o][3]);
            acc[o][3] = fmaf(b3, wB0, acc[o][3]); acc[o][3] = fmaf(b2, wB2, acc[o][3]);
        }
    }

    int ox0 = ox4 * 4;
#pragma unroll
    for (int o = 0; o < COT; ++o) {
        float* yr = y + (((size_t)n * Cout + co0 + o) * OH + oy) * OW + ox0;
#pragma unroll
        for (int j = 0; j < 4; ++j) {
            float v = acc[o][j];
            yr[j] = (ACT == 0) ? fmaxf(v, 0.0f) : tanhf(v);
        }
    }
}

// =============================== quantizer =================================
__global__ void __launch_bounds__(256) embed_norms(
    const float* __restrict__ embed, float* __restrict__ norms)
{
    int c = blockIdx.x * 256 + threadIdx.x;
    const float* e = embed + (size_t)c * 512;
    float s = 0.0f;
    for (int k = 0; k < 512; ++k) s = fmaf(e[k], e[k], s);
    norms[c] = s;
}

__global__ void __launch_bounds__(256) vq_argmin8(
    const float* __restrict__ z, const float* __restrict__ embed,
    const float* __restrict__ norms, int* __restrict__ out)
{
    int row0 = blockIdx.x * 8;
    int n    = row0 >> 8;
    int yx0  = row0 & 255;

    __shared__ float zr[8 * 512];
    const float* zn = z + ((size_t)n * 512) * 256;
    for (int i = threadIdx.x; i < 8 * 512; i += 256) {
        int r = i >> 9, c = i & 511;
        zr[i] = zn[((size_t)c << 8) + yx0 + r];
    }
    __syncthreads();

    float best[8]; int bi[8];
#pragma unroll
    for (int r = 0; r < 8; ++r) { best[r] = 3.4e38f; bi[r] = 0; }

#pragma unroll
    for (int rep = 0; rep < 4; ++rep) {
        int code = rep * 256 + threadIdx.x;
        const float4* e4 = (const float4*)(embed + (size_t)code * 512);
        float dot[8];
#pragma unroll
        for (int r = 0; r < 8; ++r) dot[r] = 0.0f;
        for (int k4 = 0; k4 < 128; ++k4) {
            float4 e = e4[k4];
#pragma unroll
            for (int r = 0; r < 8; ++r) {
                const float4 zz = *(const float4*)&zr[r * 512 + k4 * 4];
                dot[r] = fmaf(e.x, zz.x, dot[r]);
                dot[r] = fmaf(e.y, zz.y, dot[r]);
                dot[r] = fmaf(e.z, zz.z, dot[r]);
                dot[r] = fmaf(e.w, zz.w, dot[r]);
            }
        }
        float nb = norms[code];
#pragma unroll
        for (int r = 0; r < 8; ++r) {
            float d = nb - 2.0f * dot[r];
            if (d < best[r]) { best[r] = d; bi[r] = code; }
        }
    }

    __shared__ float rbd[8 * 256];
    __shared__ int   rbi[8 * 256];
#pragma unroll
    for (int r = 0; r < 8; ++r) {
        rbd[r * 256 + threadIdx.x] = best[r];
        rbi[r * 256 + threadIdx.x] = bi[r];
    }
    __syncthreads();
    for (int s = 128; s > 0; s >>= 1) {
        if ((int)threadIdx.x < s) {
#pragma unroll
            for (int r = 0; r < 8; ++r) {
                int i0 = r * 256 + threadIdx.x;
                float od = rbd[i0 + s]; int oi = rbi[i0 + s];
                float md = rbd[i0];     int mi = rbi[i0];
                if (od < md || (od == md && oi < mi)) { rbd[i0] = od; rbi[i0] = oi; }
            }
        }
        __syncthreads();
    }
    if (threadIdx.x < 8) out[row0 + threadIdx.x] = rbi[threadIdx.x * 256];
}

__global__ void __launch_bounds__(256) vq_gather(
    const int* __restrict__ vidx, const float* __restrict__ embed,
    float* __restrict__ zq)
{
    int i = blockIdx.x * 256 + threadIdx.x;
    int yx = i & 255;
    int t  = i >> 8;
    int c  = t & 511;
    int n  = t >> 9;
    int row = (n << 8) + yx;
    zq[i] = embed[(size_t)vidx[row] * 512 + c];
}

// ================================ launch ===================================
extern "C" void kernel_launch(void* const* d_in, const int* in_sizes, int n_in,
                              void* d_out, int out_size, void* d_ws, size_t ws_size,
                              hipStream_t stream)
{
    (void)in_sizes; (void)n_in; (void)out_size; (void)ws_size;
    const float* x     = (const float*)d_in[0];
    const float* ew1   = (const float*)d_in[1];
    const float* eb1   = (const float*)d_in[2];
    const float* ew2   = (const float*)d_in[3];
    const float* eb2   = (const float*)d_in[4];
    const float* ew3   = (const float*)d_in[5];
    const float* eb3   = (const float*)d_in[6];
    const float* ew4   = (const float*)d_in[7];
    const float* eb4   = (const float*)d_in[8];
    const float* dw1   = (const float*)d_in[9];
    const float* db1   = (const float*)d_in[10];
    const float* dw2   = (const float*)d_in[11];
    const float* db2   = (const float*)d_in[12];
    const float* dw3   = (const float*)d_in[13];
    const float* db3   = (const float*)d_in[14];
    const float* dw4   = (const float*)d_in[15];
    const float* db4   = (const float*)d_in[16];
    const float* embed = (const float*)d_in[17];
    float* out = (float*)d_out;

    float* A     = (float*)d_ws;                 // 128 MiB
    float* B     = A + 33554432;                 // 64 MiB
    int*   vidx  = (int*)(B + 16777216);
    float* norms = (float*)(vidx + 8192);

    dim3 b256(256), b128(128);

    // ---- encoder ----
    conv4s2_k<3, 256, 256, 64, 4, 3><<<dim3(8192), b256, 0, stream>>>(
        x, ew1, eb1, A);                                   // h1 -> A
    conv4s2_lds<64, 128, 128, 128><<<dim3(32 * 4 * 16), b256, 0, stream>>>(
        A, ew2, eb2, B);                                   // h2 -> B
    conv4s2_lds<128, 64, 64, 256><<<dim3(32 * 8 * 4), b256, 0, stream>>>(
        B, ew3, eb3, A);                                   // h3 -> A
    conv4s2_lds<256, 32, 32, 512><<<dim3(32 * 16 * 1), b256, 0, stream>>>(
        A, ew4, eb4, B);                                   // z  -> B

    // ---- quantizer ----
    embed_norms<<<dim3(4), b256, 0, stream>>>(embed, norms);
    vq_argmin8<<<dim3(1024), b256, 0, stream>>>(B, embed, norms, vidx);
    vq_gather<<<dim3(16384), b256, 0, stream>>>(vidx, embed, A);   // zq -> A

    // ---- decoder ----
    convt4s2_lds<512, 16, 16, 128><<<dim3(32 * 4 * 4), b128, 0, stream>>>(
        A, dw1, db1, B);                                   // g1 -> B
    convt4s2_lds<128, 32, 32, 64><<<dim3(32 * 2 * 16), b128, 0, stream>>>(
        B, dw2, db2, A);                                   // g2 -> A
    convt4s2_lds<64, 64, 64, 32><<<dim3(32 * 1 * 64), b128, 0, stream>>>(
        A, dw3, db3, B);                                   // g3 -> B
    convt4s2_k<32, 128, 128, 3, 3, 1, 2><<<dim3(2048), b256, 0, stream>>>(
        B, dw4, db4, out);                                 // out (tanh)
}

// Round 7
// 1868.131 us; speedup vs baseline: 20.7710x; 1.7748x over previous
//
#include <hip/hip_runtime.h>
#include <math.h>

// ---------------------------------------------------------------------------
// VQ-VAE forward. Round 7: R6 MFMA implicit-GEMM encoder with the epilogue
// store-stride bug fixed (gb + 4*i2, was 8*i2 -> half the quads unwritten).
// conv2/3/4: bf16 hi/lo split MFMA (3-product, ~fp32 accuracy).
// ---------------------------------------------------------------------------

typedef __attribute__((ext_vector_type(8))) short bf16x8;
typedef __attribute__((ext_vector_type(4))) float f32x4;
union FragU { unsigned u[4]; bf16x8 v; };

__device__ __forceinline__ unsigned bf16_rne(unsigned u) {
    return (u + 0x7FFFu + ((u >> 16) & 1u)) >> 16;
}
// pack fp32 -> u32: low16 = bf16(v), high16 = bf16(v - bf16(v))
__device__ __forceinline__ unsigned pack_split(float v) {
    unsigned u = __builtin_bit_cast(unsigned, v);
    unsigned hi = bf16_rne(u);
    float hif = __builtin_bit_cast(float, hi << 16);
    float r = v - hif;
    unsigned lo = bf16_rne(__builtin_bit_cast(unsigned, r));
    return hi | (lo << 16);
}

__global__ void __launch_bounds__(256) pack_tensor(
    const float* __restrict__ s, unsigned* __restrict__ d, int n)
{
    int i = blockIdx.x * 256 + threadIdx.x;
    if (i < n) d[i] = pack_split(s[i]);
}

// ================= MFMA conv k=4 s=2 p=1 + ReLU (implicit GEMM) ============
// GEMM: C[m][oc] = sum_k A[m][k] B[k][oc], m = (n,oy,ox) flat,
// k = ic*16 + ky*4 + kx. Block: 64 M x 128 OC, 4 waves (64M x 32OC each).
// K-chunk = 32 (2 channels). Inputs x/weights pre-packed u32(hi,lo).
template<int Cin, int H, int W, int Cout, int PACKO>
__global__ void __launch_bounds__(256) conv4s2_mfma(
    const unsigned* __restrict__ xp, const unsigned* __restrict__ wp,
    const float* __restrict__ bias, float* __restrict__ y)
{
    constexpr int OH = H / 2, OW = W / 2;
    constexpr int LOG_OW = (OW == 64) ? 6 : (OW == 32) ? 5 : 4;
    constexpr int R   = 64 / OW;            // oy rows per block
    constexpr int RT  = 2 * R + 2;          // raw input rows (halo)
    constexpr int CS  = W + 2;              // raw cols (shift +1), even
    constexpr int XEL = 2 * RT * CS;
    constexpr int XIT = (XEL + 255) / 256;
    constexpr int K   = Cin * 16;
    constexpr int NC  = Cin / 2;            // chunks (32 k each)
    constexpr int NB  = 128;
    constexpr int MBC = 32 * OH * OW / 64;  // m-blocks

    __shared__ unsigned smem[8704];         // staging: raw[XEL] + wb ; epi: C
    unsigned* raw = smem;
    unsigned* wb  = smem + ((XEL + 7) & ~7);   // [NB][36]

    int bid = blockIdx.x;
    int mb = bid % MBC, ng = bid / MBC;
    int oc0 = ng * NB;
    int m0 = mb * 64;
    int nimg = m0 / (OH * OW);
    int sp0 = m0 % (OH * OW);
    int oyb = sp0 >> LOG_OW;

    int tid  = threadIdx.x;
    int lane = tid & 63, wv = tid >> 6;
    int lm = lane & 15, q = lane >> 4;
    int n0w = wv * 32;

    const unsigned* xbase = xp + (size_t)nimg * Cin * H * W;

    // ---- precompute A-loader offsets (chunk-invariant) ----
    int  goff[XIT];
    bool gok[XIT];
#pragma unroll
    for (int s = 0; s < XIT; ++s) {
        int i = tid + 256 * s;
        goff[s] = 0; gok[s] = false;
        if (i < XEL) {
            int lc = i % CS;
            int t2 = i / CS;
            int lr = t2 % RT;
            int c  = t2 / RT;
            int gr = 2 * oyb - 1 + lr;
            int gc = lc - 1;
            bool ok = ((unsigned)gr < (unsigned)H) && ((unsigned)gc < (unsigned)W);
            goff[s] = ok ? (c * H * W + gr * W + gc) : 0;
            gok[s]  = ok;
        }
    }
    // B loader: kk = tid&31 const, nl = (tid>>5) + 8s
    const unsigned* wbase = wp + (size_t)(oc0 + (tid >> 5)) * K + (tid & 31);
    int wlds0 = (tid >> 5) * 36 + (tid & 31);

    // ---- accumulators (bias init; D: n = lane&15, m = quad*4+reg) ----
    f32x4 acc[4][2];
#pragma unroll
    for (int nt = 0; nt < 2; ++nt) {
        float b = bias[oc0 + n0w + nt * 16 + lm];
#pragma unroll
        for (int mt = 0; mt < 4; ++mt)
#pragma unroll
            for (int r = 0; r < 4; ++r) acc[mt][nt][r] = b;
    }

    unsigned pfa[XIT];
    unsigned pfb[16];

    auto load_chunk = [&](int ch) {
        const unsigned* cb = xbase + (size_t)(ch * 2) * (H * W);
#pragma unroll
        for (int s = 0; s < XIT; ++s) {
            unsigned v = 0;
            if (gok[s]) v = cb[goff[s]];
            pfa[s] = v;
        }
        const unsigned* wc = wbase + ch * 32;
#pragma unroll
        for (int s = 0; s < 16; ++s) pfb[s] = wc[(size_t)s * 8 * K];
    };
    auto store_chunk = [&]() {
#pragma unroll
        for (int s = 0; s < XIT; ++s) {
            int i = tid + 256 * s;
            if (i < XEL) raw[i] = pfa[s];
        }
#pragma unroll
        for (int s = 0; s < 16; ++s) wb[wlds0 + s * 288] = pfb[s];
    };

    load_chunk(0);
#pragma unroll 1
    for (int ch = 0; ch < NC; ++ch) {
        __syncthreads();
        store_chunk();
        __syncthreads();
        if (ch + 1 < NC) load_chunk(ch + 1);

        // ---- B fragments (n = lane&15, k = q*8+j) ----
        FragU bhi[2], blo[2];
#pragma unroll
        for (int nt = 0; nt < 2; ++nt) {
            const unsigned* bp = &wb[(n0w + nt * 16 + lm) * 36 + q * 8];
            uint4 p0 = *(const uint4*)bp;
            uint4 p1 = *(const uint4*)(bp + 4);
            unsigned e0 = p0.x, e1 = p0.y, e2 = p0.z, e3 = p0.w;
            unsigned e4 = p1.x, e5 = p1.y, e6 = p1.z, e7 = p1.w;
            bhi[nt].u[0] = (e0 & 0xffffu) | (e1 << 16);
            bhi[nt].u[1] = (e2 & 0xffffu) | (e3 << 16);
            bhi[nt].u[2] = (e4 & 0xffffu) | (e5 << 16);
            bhi[nt].u[3] = (e6 & 0xffffu) | (e7 << 16);
            blo[nt].u[0] = (e0 >> 16) | (e1 & 0xffff0000u);
            blo[nt].u[1] = (e2 >> 16) | (e3 & 0xffff0000u);
            blo[nt].u[2] = (e4 >> 16) | (e5 & 0xffff0000u);
            blo[nt].u[3] = (e6 >> 16) | (e7 & 0xffff0000u);
        }
        // ---- A fragments (m = lane&15, k = q*8+j) + MFMA ----
#pragma unroll
        for (int mt = 0; mt < 4; ++mt) {
            int m = mt * 16 + lm;
            int oyl = m >> LOG_OW, oxl = m & (OW - 1);
            int c = q >> 1, rb = 2 * oyl + (q & 1) * 2;
            const unsigned* rp = &raw[(c * RT + rb) * CS + 2 * oxl];
            uint2 a0 = *(const uint2*)rp;
            uint2 a1 = *(const uint2*)(rp + 2);
            uint2 a2 = *(const uint2*)(rp + CS);
            uint2 a3 = *(const uint2*)(rp + CS + 2);
            FragU ahi, alo;
            ahi.u[0] = (a0.x & 0xffffu) | (a0.y << 16);
            ahi.u[1] = (a1.x & 0xffffu) | (a1.y << 16);
            ahi.u[2] = (a2.x & 0xffffu) | (a2.y << 16);
            ahi.u[3] = (a3.x & 0xffffu) | (a3.y << 16);
            alo.u[0] = (a0.x >> 16) | (a0.y & 0xffff0000u);
            alo.u[1] = (a1.x >> 16) | (a1.y & 0xffff0000u);
            alo.u[2] = (a2.x >> 16) | (a2.y & 0xffff0000u);
            alo.u[3] = (a3.x >> 16) | (a3.y & 0xffff0000u);
#pragma unroll
            for (int nt = 0; nt < 2; ++nt) {
                acc[mt][nt] = __builtin_amdgcn_mfma_f32_16x16x32_bf16(
                    ahi.v, bhi[nt].v, acc[mt][nt], 0, 0, 0);
                acc[mt][nt] = __builtin_amdgcn_mfma_f32_16x16x32_bf16(
                    ahi.v, blo[nt].v, acc[mt][nt], 0, 0, 0);
                acc[mt][nt] = __builtin_amdgcn_mfma_f32_16x16x32_bf16(
                    alo.v, bhi[nt].v, acc[mt][nt], 0, 0, 0);
            }
        }
    }

    // ---- epilogue: transpose via LDS, relu, coalesced NCHW store ----
    __syncthreads();
    float* cs = (float*)smem;               // [NB][68]
#pragma unroll
    for (int mt = 0; mt < 4; ++mt)
#pragma unroll
        for (int nt = 0; nt < 2; ++nt) {
            int nl = n0w + nt * 16 + lm;
#pragma unroll
            for (int r = 0; r < 4; ++r)
                cs[nl * 68 + mt * 16 + q * 4 + r] = acc[mt][nt][r];
        }
    __syncthreads();
    {
        int nl = tid >> 1, half = tid & 1;
        size_t gb = ((size_t)(nimg * Cout + oc0 + nl)) * (OH * OW) + sp0 + half * 32;
#pragma unroll
        for (int i2 = 0; i2 < 8; ++i2) {
            float4 v = *(float4*)&cs[nl * 68 + half * 32 + 4 * i2];
            v.x = fmaxf(v.x, 0.0f); v.y = fmaxf(v.y, 0.0f);
            v.z = fmaxf(v.z, 0.0f); v.w = fmaxf(v.w, 0.0f);
            if (PACKO) {
                uint4 p;
                p.x = pack_split(v.x); p.y = pack_split(v.y);
                p.z = pack_split(v.z); p.w = pack_split(v.w);
                *(uint4*)((unsigned*)y + gb + 4 * i2) = p;   // FIXED (was 8*i2)
            } else {
                *(float4*)(y + gb + 4 * i2) = v;             // FIXED (was 8*i2)
            }
        }
    }
}

// ================= direct conv (conv1, packs output) =======================
template<int Cin, int H, int W, int OCT, int UNR, bool INT>
__device__ __forceinline__ void conv_core(
    const float* __restrict__ xn, const float* __restrict__ wbase,
    int iy0, int ix0, float (&acc)[OCT][4])
{
#pragma unroll UNR
    for (int ic = 0; ic < Cin; ++ic) {
        const float* xc = xn + (size_t)ic * (H * W);
        float xv[4][10];
#pragma unroll
        for (int ky = 0; ky < 4; ++ky) {
            int iy = iy0 + ky;
            if (INT) {
                const float* xr = xc + (size_t)iy * W;
#pragma unroll
                for (int j = 0; j < 10; ++j) xv[ky][j] = xr[ix0 + j];
            } else {
                bool rv = ((unsigned)iy < (unsigned)H);
                const float* xr = xc + (size_t)(rv ? iy : 0) * W;
#pragma unroll
                for (int j = 0; j < 10; ++j) {
                    int ix = ix0 + j;
                    bool cv = rv && ((unsigned)ix < (unsigned)W);
                    xv[ky][j] = cv ? xr[cv ? ix : 0] : 0.0f;
                }
            }
        }
#pragma unroll
        for (int o = 0; o < OCT; ++o) {
            const float* wr = wbase + (size_t)o * (Cin * 16) + ic * 16;
#pragma unroll
            for (int ky = 0; ky < 4; ++ky) {
                float w0 = wr[ky * 4 + 0], w1 = wr[ky * 4 + 1];
                float w2 = wr[ky * 4 + 2], w3 = wr[ky * 4 + 3];
#pragma unroll
                for (int j = 0; j < 4; ++j) {
                    acc[o][j] = fmaf(xv[ky][2 * j],     w0, acc[o][j]);
                    acc[o][j] = fmaf(xv[ky][2 * j + 1], w1, acc[o][j]);
                    acc[o][j] = fmaf(xv[ky][2 * j + 2], w2, acc[o][j]);
                    acc[o][j] = fmaf(xv[ky][2 * j + 3], w3, acc[o][j]);
                }
            }
        }
    }
}

template<int Cin, int H, int W, int Cout, int OCT, int UNR, int PACKO>
__global__ void __launch_bounds__(256) conv4s2_k(
    const float* __restrict__ x, const float* __restrict__ w,
    const float* __restrict__ bias, float* __restrict__ y)
{
    constexpr int OH = H / 2, OW = W / 2, OWq = OW / 4;
    int id = blockIdx.x * 256 + threadIdx.x;
    int ox4 = id % OWq; int t = id / OWq;
    int oy  = t % OH;   t /= OH;
    int ocg = t % (Cout / OCT);
    int n   = t / (Cout / OCT);
    int oc0 = __builtin_amdgcn_readfirstlane(ocg * OCT);
    n       = __builtin_amdgcn_readfirstlane(n);

    float acc[OCT][4];
#pragma unroll
    for (int o = 0; o < OCT; ++o) {
        float b = bias[oc0 + o];
#pragma unroll
        for (int j = 0; j < 4; ++j) acc[o][j] = b;
    }

    const float* xn    = x + (size_t)n * Cin * H * W;
    const float* wbase = w + (size_t)oc0 * Cin * 16;
    int iy0 = 2 * oy - 1;
    int ix0 = 8 * ox4 - 1;

    bool interior = (oy >= 1) && (oy <= OH - 2) && (ox4 >= 1) && (ox4 <= OWq - 2);
    if (interior) conv_core<Cin, H, W, OCT, UNR, true >(xn, wbase, iy0, ix0, acc);
    else          conv_core<Cin, H, W, OCT, UNR, false>(xn, wbase, iy0, ix0, acc);

    int ox0 = ox4 * 4;
#pragma unroll
    for (int o = 0; o < OCT; ++o) {
        size_t gb = (((size_t)n * Cout + oc0 + o) * OH + oy) * OW + ox0;
#pragma unroll
        for (int j = 0; j < 4; ++j) {
            float v = fmaxf(acc[o][j], 0.0f);
            if (PACKO) ((unsigned*)y)[gb + j] = pack_split(v);
            else       y[gb + j] = v;
        }
    }
}

// =============== LDS-staged ConvTranspose2d (decoder, fp32) ================
template<int Cin, int H, int W, int Cout>
__global__ void __launch_bounds__(128) convt4s2_lds(
    const float* __restrict__ x, const float* __restrict__ w,
    const float* __restrict__ bias, float* __restrict__ y)
{
    constexpr int OH = 2 * H, OW = 2 * W;
    constexpr int SPX = OW / 16, SPT = (OH / 16) * SPX;
    constexpr int NC = Cin / 4;
    constexpr int XEL = 4 * 10 * 12;
    constexpr int XIT = (XEL + 127) / 128;
    constexpr int WIT = 16;

    __shared__ float xt[4][10][12];
    __shared__ float wt[4][16][32];

    int bid = blockIdx.x;
    int st  = bid % SPT; int t = bid / SPT;
    int cog = t % (Cout / 32);
    int n   = t / (Cout / 32);
    int oyb = (st / SPX) * 16, oxb = (st % SPX) * 16;
    int co0 = cog * 32;
    int ib = oyb / 2, jb = oxb / 2;

    int tid = threadIdx.x;
    int tx = tid & 3, ty = (tid >> 2) & 3, tc = tid >> 4;

    float acc[4][4][4];
#pragma unroll
    for (int o = 0; o < 4; ++o) {
        float b = bias[co0 + 4 * tc + o];
#pragma unroll
        for (int r = 0; r < 4; ++r)
#pragma unroll
            for (int j = 0; j < 4; ++j) acc[r][o][j] = b;
    }

    const float* xn = x + (size_t)n * Cin * H * W;
    float pfx[XIT];
    float pfw[WIT];

    auto load_chunk = [&](int c0) {
#pragma unroll
        for (int k = 0; k < XIT; ++k) {
            int i = tid + 128 * k;
            float v = 0.0f;
            if (i < XEL) {
                int lc  = i % 12;
                int r2  = i / 12;
                int lr  = r2 % 10;
                int icc = r2 / 10;
                int gr = ib - 1 + lr;
                int gc = jb - 1 + lc;
                if ((unsigned)gr < (unsigned)H && (unsigned)gc < (unsigned)W)
                    v = xn[((size_t)(c0 + icc) * H + gr) * W + gc];
            }
            pfx[k] = v;
        }
#pragma unroll
        for (int k = 0; k < WIT; ++k) {
            int i = tid + 128 * k;
            int col = i & 31;
            int kk  = (i >> 5) & 15;
            int icc = i >> 9;
            pfw[k] = w[((size_t)(c0 + icc) * Cout + co0 + col) * 16 + kk];
        }
    };
    auto store_chunk = [&]() {
#pragma unroll
        for (int k = 0; k < XIT; ++k) {
            int i = tid + 128 * k;
            if (i < XEL) ((float*)xt)[i] = pfx[k];
        }
#pragma unroll
        for (int k = 0; k < WIT; ++k) {
            int i = tid + 128 * k;
            int col = i & 31;
            int kk  = (i >> 5) & 15;
            int icc = i >> 9;
            wt[icc][kk][col] = pfw[k];
        }
    };

    load_chunk(0);
#pragma unroll 1
    for (int c = 0; c < NC; ++c) {
        __syncthreads();
        store_chunk();
        __syncthreads();
        if (c + 1 < NC) load_chunk((c + 1) * 4);

#pragma unroll 1
        for (int icc = 0; icc < 4; ++icc) {
            float xr[4][4];
#pragma unroll
            for (int qq = 0; qq < 4; ++qq) {
                const float* rp = &xt[icc][2 * ty + qq][2 * tx];
                float2 u = *(const float2*)rp;
                float2 v = *(const float2*)(rp + 2);
                xr[qq][0] = u.x; xr[qq][1] = u.y; xr[qq][2] = v.x; xr[qq][3] = v.y;
            }
#pragma unroll
            for (int pp = 0; pp < 2; ++pp) {
                const int kyA = 1 - pp, kyB = 3 - pp;
                float wA[4][4], wB[4][4];
#pragma unroll
                for (int kx = 0; kx < 4; ++kx) {
                    float4 ta = *(const float4*)&wt[icc][kyA * 4 + kx][4 * tc];
                    float4 tb = *(const float4*)&wt[icc][kyB * 4 + kx][4 * tc];
                    wA[kx][0] = ta.x; wA[kx][1] = ta.y; wA[kx][2] = ta.z; wA[kx][3] = ta.w;
                    wB[kx][0] = tb.x; wB[kx][1] = tb.y; wB[kx][2] = tb.z; wB[kx][3] = tb.w;
                }
#pragma unroll
                for (int rr = 0; rr < 2; ++rr) {
                    const int r  = pp + 2 * rr;
                    const int Ai = 1 + ((r + 1) >> 1);
                    const float* a = xr[Ai];
                    const float* b = xr[Ai - 1];
#pragma unroll
                    for (int o = 0; o < 4; ++o) {
                        float s0 = acc[r][o][0], s1 = acc[r][o][1];
                        float s2 = acc[r][o][2], s3 = acc[r][o][3];
                        s0 = fmaf(a[1], wA[1][o], s0); s0 = fmaf(a[0], wA[3][o], s0);
                        s0 = fmaf(b[1], wB[1][o], s0); s0 = fmaf(b[0], wB[3][o], s0);
                        s1 = fmaf(a[2], wA[0][o], s1); s1 = fmaf(a[1], wA[2][o], s1);
                        s1 = fmaf(b[2], wB[0][o], s1); s1 = fmaf(b[1], wB[2][o], s1);
                        s2 = fmaf(a[2], wA[1][o], s2); s2 = fmaf(a[1], wA[3][o], s2);
                        s2 = fmaf(b[2], wB[1][o], s2); s2 = fmaf(b[1], wB[3][o], s2);
                        s3 = fmaf(a[3], wA[0][o], s3); s3 = fmaf(a[2], wA[2][o], s3);
                        s3 = fmaf(b[3], wB[0][o], s3); s3 = fmaf(b[2], wB[2][o], s3);
                        acc[r][o][0] = s0; acc[r][o][1] = s1;
                        acc[r][o][2] = s2; acc[r][o][3] = s3;
                    }
                }
            }
        }
    }

#pragma unroll
    for (int r = 0; r < 4; ++r) {
        int oy = oyb + 4 * ty + r;
#pragma unroll
        for (int o = 0; o < 4; ++o) {
            float* yr = y + (((size_t)n * Cout + co0 + 4 * tc + o) * OH + oy) * OW
                          + oxb + 4 * tx;
            float4 v;
            v.x = fmaxf(acc[r][o][0], 0.0f);
            v.y = fmaxf(acc[r][o][1], 0.0f);
            v.z = fmaxf(acc[r][o][2], 0.0f);
            v.w = fmaxf(acc[r][o][3], 0.0f);
            *(float4*)yr = v;
        }
    }
}

// ================= direct convT (g4, tanh) =================================
template<int Cin, int H, int W, int Cout, int COT, int ACT, int UNR>
__global__ void __launch_bounds__(256) convt4s2_k(
    const float* __restrict__ x, const float* __restrict__ w,
    const float* __restrict__ bias, float* __restrict__ y)
{
    constexpr int OH = 2 * H, OW = 2 * W, OWq = OW / 4;
    int id = blockIdx.x * 256 + threadIdx.x;
    int ox4 = id % OWq; int t = id / OWq;
    int oy  = t % OH;   t /= OH;
    int cog = t % (Cout / COT);
    int n   = t / (Cout / COT);
    int co0 = __builtin_amdgcn_readfirstlane(cog * COT);
    n       = __builtin_amdgcn_readfirstlane(n);

    int p   = (oy + 1) & 1;
    int iyA = (oy + 1 - p) >> 1;
    int iyB = iyA - 1;
    bool vA = (iyA < H);
    bool vB = (iyB >= 0);
    int iyAc = vA ? iyA : 0, iyBc = vB ? iyB : 0;

    int t0 = 2 * ox4;
    bool c0 = (t0 - 1 >= 0);
    bool c3 = (t0 + 2 <= W - 1);
    int j0 = c0 ? t0 - 1 : 0;
    int j3 = c3 ? t0 + 2 : 0;

    float acc[COT][4];
#pragma unroll
    for (int o = 0; o < COT; ++o) {
        float b = bias[co0 + o];
#pragma unroll
        for (int j = 0; j < 4; ++j) acc[o][j] = b;
    }

    const float* xn = x + (size_t)n * Cin * H * W;

#pragma unroll UNR
    for (int ci = 0; ci < Cin; ++ci) {
        const float* xc  = xn + (size_t)ci * (H * W);
        const float* xrA = xc + (size_t)iyAc * W;
        const float* xrB = xc + (size_t)iyBc * W;
        float a0 = (vA && c0) ? xrA[j0]     : 0.0f;
        float a1 =  vA        ? xrA[t0]     : 0.0f;
        float a2 =  vA        ? xrA[t0 + 1] : 0.0f;
        float a3 = (vA && c3) ? xrA[j3]     : 0.0f;
        float b0 = (vB && c0) ? xrB[j0]     : 0.0f;
        float b1 =  vB        ? xrB[t0]     : 0.0f;
        float b2 =  vB        ? xrB[t0 + 1] : 0.0f;
        float b3 = (vB && c3) ? xrB[j3]     : 0.0f;

        const float* wci = w + ((size_t)ci * Cout + co0) * 16;
#pragma unroll
        for (int o = 0; o < COT; ++o) {
            const float* wr = wci + (size_t)o * 16;
            float wA0 = wr[p * 4 + 0], wA1 = wr[p * 4 + 1];
            float wA2 = wr[p * 4 + 2], wA3 = wr[p * 4 + 3];
            float wB0 = wr[(p + 2) * 4 + 0], wB1 = wr[(p + 2) * 4 + 1];
            float wB2 = wr[(p + 2) * 4 + 2], wB3 = wr[(p + 2) * 4 + 3];
            acc[o][0] = fmaf(a1, wA1, acc[o][0]); acc[o][0] = fmaf(a0, wA3, acc[o][0]);
            acc[o][0] = fmaf(b1, wB1, acc[o][0]); acc[o][0] = fmaf(b0, wB3, acc[o][0]);
            acc[o][1] = fmaf(a2, wA0, acc[o][1]); acc[o][1] = fmaf(a1, wA2, acc[o][1]);
            acc[o][1] = fmaf(b2, wB0, acc[o][1]); acc[o][1] = fmaf(b1, wB2, acc[o][1]);
            acc[o][2] = fmaf(a2, wA1, acc[o][2]); acc[o][2] = fmaf(a1, wA3, acc[o][2]);
            acc[o][2] = fmaf(b2, wB1, acc[o][2]); acc[o][2] = fmaf(b1, wB3, acc[o][2]);
            acc[o][3] = fmaf(a3, wA0, acc[o][3]); acc[o][3] = fmaf(a2, wA2, acc[o][3]);
            acc[o][3] = fmaf(b3, wB0, acc[o][3]); acc[o][3] = fmaf(b2, wB2, acc[o][3]);
        }
    }

    int ox0 = ox4 * 4;
#pragma unroll
    for (int o = 0; o < COT; ++o) {
        float* yr = y + (((size_t)n * Cout + co0 + o) * OH + oy) * OW + ox0;
#pragma unroll
        for (int j = 0; j < 4; ++j) {
            float v = acc[o][j];
            yr[j] = (ACT == 0) ? fmaxf(v, 0.0f) : tanhf(v);
        }
    }
}

// =============================== quantizer =================================
__global__ void __launch_bounds__(256) embed_norms(
    const float* __restrict__ embed, float* __restrict__ norms)
{
    int c = blockIdx.x * 256 + threadIdx.x;
    const float* e = embed + (size_t)c * 512;
    float s = 0.0f;
    for (int k = 0; k < 512; ++k) s = fmaf(e[k], e[k], s);
    norms[c] = s;
}

__global__ void __launch_bounds__(256) vq_argmin8(
    const float* __restrict__ z, const float* __restrict__ embed,
    const float* __restrict__ norms, int* __restrict__ out)
{
    int row0 = blockIdx.x * 8;
    int n    = row0 >> 8;
    int yx0  = row0 & 255;

    __shared__ float zr[8 * 512];
    const float* zn = z + ((size_t)n * 512) * 256;
    for (int i = threadIdx.x; i < 8 * 512; i += 256) {
        int r = i >> 9, c = i & 511;
        zr[i] = zn[((size_t)c << 8) + yx0 + r];
    }
    __syncthreads();

    float best[8]; int bi[8];
#pragma unroll
    for (int r = 0; r < 8; ++r) { best[r] = 3.4e38f; bi[r] = 0; }

#pragma unroll
    for (int rep = 0; rep < 4; ++rep) {
        int code = rep * 256 + threadIdx.x;
        const float4* e4 = (const float4*)(embed + (size_t)code * 512);
        float dot[8];
#pragma unroll
        for (int r = 0; r < 8; ++r) dot[r] = 0.0f;
        for (int k4 = 0; k4 < 128; ++k4) {
            float4 e = e4[k4];
#pragma unroll
            for (int r = 0; r < 8; ++r) {
                const float4 zz = *(const float4*)&zr[r * 512 + k4 * 4];
                dot[r] = fmaf(e.x, zz.x, dot[r]);
                dot[r] = fmaf(e.y, zz.y, dot[r]);
                dot[r] = fmaf(e.z, zz.z, dot[r]);
                dot[r] = fmaf(e.w, zz.w, dot[r]);
            }
        }
        float nb = norms[code];
#pragma unroll
        for (int r = 0; r < 8; ++r) {
            float d = nb - 2.0f * dot[r];
            if (d < best[r]) { best[r] = d; bi[r] = code; }
        }
    }

    __shared__ float rbd[8 * 256];
    __shared__ int   rbi[8 * 256];
#pragma unroll
    for (int r = 0; r < 8; ++r) {
        rbd[r * 256 + threadIdx.x] = best[r];
        rbi[r * 256 + threadIdx.x] = bi[r];
    }
    __syncthreads();
    for (int s = 128; s > 0; s >>= 1) {
        if ((int)threadIdx.x < s) {
#pragma unroll
            for (int r = 0; r < 8; ++r) {
                int i0 = r * 256 + threadIdx.x;
                float od = rbd[i0 + s]; int oi = rbi[i0 + s];
                float md = rbd[i0];     int mi = rbi[i0];
                if (od < md || (od == md && oi < mi)) { rbd[i0] = od; rbi[i0] = oi; }
            }
        }
        __syncthreads();
    }
    if (threadIdx.x < 8) out[row0 + threadIdx.x] = rbi[threadIdx.x * 256];
}

__global__ void __launch_bounds__(256) vq_gather(
    const int* __restrict__ vidx, const float* __restrict__ embed,
    float* __restrict__ zq)
{
    int i = blockIdx.x * 256 + threadIdx.x;
    int yx = i & 255;
    int t  = i >> 8;
    int c  = t & 511;
    int n  = t >> 9;
    int row = (n << 8) + yx;
    zq[i] = embed[(size_t)vidx[row] * 512 + c];
}

// ================================ launch ===================================
extern "C" void kernel_launch(void* const* d_in, const int* in_sizes, int n_in,
                              void* d_out, int out_size, void* d_ws, size_t ws_size,
                              hipStream_t stream)
{
    (void)in_sizes; (void)n_in; (void)out_size; (void)ws_size;
    const float* x     = (const float*)d_in[0];
    const float* ew1   = (const float*)d_in[1];
    const float* eb1   = (const float*)d_in[2];
    const float* ew2   = (const float*)d_in[3];
    const float* eb2   = (const float*)d_in[4];
    const float* ew3   = (const float*)d_in[5];
    const float* eb3   = (const float*)d_in[6];
    const float* ew4   = (const float*)d_in[7];
    const float* eb4   = (const float*)d_in[8];
    const float* dw1   = (const float*)d_in[9];
    const float* db1   = (const float*)d_in[10];
    const float* dw2   = (const float*)d_in[11];
    const float* db2   = (const float*)d_in[12];
    const float* dw3   = (const float*)d_in[13];
    const float* db3   = (const float*)d_in[14];
    const float* dw4   = (const float*)d_in[15];
    const float* db4   = (const float*)d_in[16];
    const float* embed = (const float*)d_in[17];
    float* out = (float*)d_out;

    // ---- workspace layout (u32 units). Peak identical to proven R5 usage.
    unsigned* W0   = (unsigned*)d_ws;             // 33,554,432 u32 region
    unsigned* h1p  = W0;                          // conv1 out (dead after conv2)
    unsigned* h2p  = W0 + 33554432;               // 16,777,216 u32 region
    unsigned* h3p  = W0;                          // overlays dead h1p
    float*    z    = (float*)(W0 + 8388608);
    float*    zq   = (float*)(W0 + 12582912);
    float*    P0   = (float*)(W0 + 16777216);     // g1 out (4.19M)
    float*    P1   = (float*)(W0 + 20971520);     // g2 out (8.39M)
    int*      vidx = (int*)(W0 + 29360128);
    float*    norms= (float*)(W0 + 29368320);
    float*    g3o  = (float*)h2p;                 // g3 out (16.78M, h2p dead)

    // packed weights live in d_out until g4 overwrites it
    unsigned* wp2 = (unsigned*)d_out;             // 131,072
    unsigned* wp3 = wp2 + 131072;                 // 524,288
    unsigned* wp4 = wp2 + 655360;                 // 2,097,152

    dim3 b256(256), b128(128);

    // ---- pre-pass: pack weights fp32 -> u32(hi,lo) ----
    pack_tensor<<<dim3(512),  b256, 0, stream>>>(ew2, wp2, 131072);
    pack_tensor<<<dim3(2048), b256, 0, stream>>>(ew3, wp3, 524288);
    pack_tensor<<<dim3(8192), b256, 0, stream>>>(ew4, wp4, 2097152);

    // ---- encoder ----
    conv4s2_k<3, 256, 256, 64, 4, 3, 1><<<dim3(8192), b256, 0, stream>>>(
        x, ew1, eb1, (float*)h1p);                         // h1 (packed)
    conv4s2_mfma<64, 128, 128, 128, 1><<<dim3(2048), b256, 0, stream>>>(
        h1p, wp2, eb2, (float*)h2p);                       // h2 (packed)
    conv4s2_mfma<128, 64, 64, 256, 1><<<dim3(1024), b256, 0, stream>>>(
        h2p, wp3, eb3, (float*)h3p);                       // h3 (packed)
    conv4s2_mfma<256, 32, 32, 512, 0><<<dim3(512), b256, 0, stream>>>(
        h3p, wp4, eb4, z);                                 // z (fp32)

    // ---- quantizer ----
    embed_norms<<<dim3(4), b256, 0, stream>>>(embed, norms);
    vq_argmin8<<<dim3(1024), b256, 0, stream>>>(z, embed, norms, vidx);
    vq_gather<<<dim3(16384), b256, 0, stream>>>(vidx, embed, zq);

    // ---- decoder ----
    convt4s2_lds<512, 16, 16, 128><<<dim3(32 * 4 * 4), b128, 0, stream>>>(
        zq, dw1, db1, P0);
    convt4s2_lds<128, 32, 32, 64><<<dim3(32 * 2 * 16), b128, 0, stream>>>(
        P0, dw2, db2, P1);
    convt4s2_lds<64, 64, 64, 32><<<dim3(32 * 1 * 64), b128, 0, stream>>>(
        P1, dw3, db3, g3o);
    convt4s2_k<32, 128, 128, 3, 3, 1, 2><<<dim3(2048), b256, 0, stream>>>(
        g3o, dw4, db4, out);                               // tanh -> d_out
}